// Round 1
// baseline (1027.108 us; speedup 1.0000x reference)
//
#include <hip/hip_runtime.h>
#include <hip/hip_bf16.h>

// Problem constants (ContextualAttention):
//  B=2, C=128, H=W=96, rate=2 -> h=w=48, L=2304, kernel=4, KSIZE=3, SCALE=10
#define Cc   128
#define Hh   96
#define hs   48
#define Ls   2304      // 48*48
#define CK   2048      // C*16

// ---------------- small kernels ----------------

__global__ __launch_bounds__(256) void subsample_k(const float* __restrict__ x2, float* __restrict__ X2S) {
    int idx = blockIdx.x * 256 + threadIdx.x;           // < 128*48*48
    if (idx >= Cc * Ls) return;
    int j = idx % hs, i = (idx / hs) % hs, c = idx / Ls;
    X2S[idx] = x2[c * (Hh * Hh) + (2 * i) * Hh + 2 * j];
}

__global__ __launch_bounds__(256) void mm_k(const float* __restrict__ mask, float* __restrict__ MM) {
    int l = blockIdx.x * 256 + threadIdx.x;
    if (l >= Ls) return;
    int ly = l / hs, lx = l % hs;
    float s = 0.f;
    for (int dy = -1; dy <= 1; ++dy)
        for (int dx = -1; dx <= 1; ++dx) {
            int yy = ly + dy, xx = lx + dx;
            if ((unsigned)yy < (unsigned)hs && (unsigned)xx < (unsigned)hs) s += mask[yy * hs + xx];
        }
    float m = s * (1.0f / 9.0f);
    MM[l] = (m == 0.0f) ? 1.0f : 0.0f;
}

// 3-tap over dx (pixel-space validity, separable pass 1): H[l,p] = sum_dx G[l+dx, p+dx]
__global__ __launch_bounds__(256) void taps_dx_k(const float* __restrict__ G, float* __restrict__ H) {
    int j = blockIdx.x * 256 + threadIdx.x;   // p
    int i = blockIdx.y;                       // l
    int lx = i % hs, px = j % hs;
    float s = 0.f;
#pragma unroll
    for (int d = -1; d <= 1; ++d) {
        if ((unsigned)(lx + d) < (unsigned)hs && (unsigned)(px + d) < (unsigned)hs)
            s += G[(i + d) * Ls + (j + d)];
    }
    H[i * Ls + j] = s;
}

// pass 2 over dy: S[l,p] = sum_dy H[l+48dy, p+48dy]
__global__ __launch_bounds__(256) void taps_dy_k(const float* __restrict__ H, float* __restrict__ S) {
    int j = blockIdx.x * 256 + threadIdx.x;
    int i = blockIdx.y;
    int ly = i / hs, py = j / hs;
    float s = 0.f;
#pragma unroll
    for (int d = -1; d <= 1; ++d) {
        if ((unsigned)(ly + d) < (unsigned)hs && (unsigned)(py + d) < (unsigned)hs)
            s += H[(i + hs * d) * Ls + (j + hs * d)];
    }
    S[i * Ls + j] = s;
}

__global__ __launch_bounds__(256) void rnorm_k(const float* __restrict__ S, float* __restrict__ RN) {
    int l = blockIdx.x * 256 + threadIdx.x;
    if (l >= Ls) return;
    RN[l] = 1.0f / fmaxf(sqrtf(S[l * Ls + l]), 1e-4f);
}

// fuse1 along flat-index diagonal, with row scale 1/norm folded in:
// O[i,j] = sum_d S[i+d, j+d] * RN[i+d]
__global__ __launch_bounds__(256) void fuse1_k(const float* __restrict__ S, const float* __restrict__ RN,
                                               float* __restrict__ O) {
    int j = blockIdx.x * 256 + threadIdx.x;
    int i = blockIdx.y;
    float s = 0.f;
#pragma unroll
    for (int d = -1; d <= 1; ++d) {
        int ii = i + d, jj = j + d;
        if ((unsigned)ii < (unsigned)Ls && (unsigned)jj < (unsigned)Ls)
            s += S[ii * Ls + jj] * RN[ii];
    }
    O[i * Ls + j] = s;
}

// fuse2: diagonal fuse in transposed flattening. tau(y*48+x) = x*48+y.
// O[i,j] = sum_d A[tau(tau(i)+d), tau(tau(j)+d)], zero when tau(i)+d outside [0,L)
__global__ __launch_bounds__(256) void fuse2_k(const float* __restrict__ A, float* __restrict__ O) {
    int j = blockIdx.x * 256 + threadIdx.x;
    int i = blockIdx.y;
    int iy = i / hs, ix = i % hs; int ip = ix * hs + iy;
    int jy = j / hs, jx = j % hs; int jp = jx * hs + jy;
    float s = 0.f;
#pragma unroll
    for (int d = -1; d <= 1; ++d) {
        int i2 = ip + d, j2 = jp + d;
        if ((unsigned)i2 < (unsigned)Ls && (unsigned)j2 < (unsigned)Ls) {
            int r = (i2 % hs) * hs + i2 / hs;
            int cc = (j2 % hs) * hs + j2 / hs;
            s += A[r * Ls + cc];
        }
    }
    O[i * Ls + j] = s;
}

// Softmax over l (rows) per column p; writes transposed result AT[p, l].
// in: Y[l*L + p]; vals = Y * MM[l] * 10; softmax over l; out = max(soft * MM[l], 1e-8)
__global__ __launch_bounds__(256) void softmax_T_k(const float* __restrict__ Y, const float* __restrict__ MM,
                                                   float* __restrict__ AT) {
    const int p = blockIdx.x;
    const int t = threadIdx.x;
    float v[9];
    float mx = -3.4e38f;
#pragma unroll
    for (int i = 0; i < 9; ++i) {
        int l = i * 256 + t;
        v[i] = Y[l * Ls + p] * MM[l] * 10.0f;
        mx = fmaxf(mx, v[i]);
    }
    for (int off = 32; off; off >>= 1) mx = fmaxf(mx, __shfl_xor(mx, off));
    __shared__ float sred[4];
    __shared__ float ssum[4];
    int wv = t >> 6;
    if ((t & 63) == 0) sred[wv] = mx;
    __syncthreads();
    mx = fmaxf(fmaxf(sred[0], sred[1]), fmaxf(sred[2], sred[3]));
    float e[9];
    float sum = 0.f;
#pragma unroll
    for (int i = 0; i < 9; ++i) { e[i] = expf(v[i] - mx); sum += e[i]; }
    for (int off = 32; off; off >>= 1) sum += __shfl_xor(sum, off);
    if ((t & 63) == 0) ssum[wv] = sum;
    __syncthreads();
    sum = ssum[0] + ssum[1] + ssum[2] + ssum[3];
    float rs = 1.0f / sum;
#pragma unroll
    for (int i = 0; i < 9; ++i) {
        int l = i * 256 + t;
        AT[p * Ls + l] = fmaxf(e[i] * rs * MM[l], 1e-8f);
    }
}

// raw_w gather: RW[l*2048 + c*16 + a*4 + b] = x1[c, 2ly+a-1, 2lx+b-1] (zero pad)
__global__ __launch_bounds__(256) void gather_rw_k(const float* __restrict__ x1, float* __restrict__ RW) {
    int idx = blockIdx.x * 256 + threadIdx.x;          // < 2304*2048
    if (idx >= Ls * CK) return;
    int ck = idx & (CK - 1), p = idx >> 11;
    int c = ck >> 4, a = (ck >> 2) & 3, b2 = ck & 3;
    int ly = p / hs, lx = p % hs;
    int u = 2 * ly + a - 1, vv = 2 * lx + b2 - 1;
    RW[idx] = ((unsigned)u < (unsigned)Hh && (unsigned)vv < (unsigned)Hh) ? x1[c * (Hh * Hh) + u * Hh + vv] : 0.0f;
}

// out[c,Y,X] = 0.25 * sum over <=4 covering (i,j,a,b): T[(i*48+j)*2048 + c*16 + a*4 + b]
__global__ __launch_bounds__(256) void scatter_k(const float* __restrict__ T, float* __restrict__ out) {
    int idx = blockIdx.x * 256 + threadIdx.x;          // < 128*96*96
    if (idx >= Cc * Hh * Hh) return;
    int X = idx % Hh, Y = (idx / Hh) % Hh, c = idx / (Hh * Hh);
    int a0 = (Y + 1) & 1;
    int b0 = (X + 1) & 1;
    float s = 0.f;
#pragma unroll
    for (int ai = 0; ai < 2; ++ai) {
        int a = a0 + 2 * ai;
        int i = (Y + 1 - a) >> 1;
        if ((unsigned)i >= (unsigned)hs) continue;
#pragma unroll
        for (int bi = 0; bi < 2; ++bi) {
            int b2 = b0 + 2 * bi;
            int jj = (X + 1 - b2) >> 1;
            if ((unsigned)jj >= (unsigned)hs) continue;
            s += T[(i * hs + jj) * CK + c * 16 + a * 4 + b2];
        }
    }
    out[idx] = 0.25f * s;
}

// ---------------- tiled f32 GEMM ----------------
// C[M x N] = A * B.  ATRANS: A stored K x M (A[k*M+m]); else M x K row-major.
// B stored K x N row-major. BM=128, BN=64, BK=8; 256 threads; 8x4 microtile.
template <bool ATRANS>
__global__ __launch_bounds__(256) void sgemm_k(const float* __restrict__ A, const float* __restrict__ B,
                                               float* __restrict__ C, int M, int N, int K) {
    __shared__ float As[8][128];
    __shared__ float Bs[8][64];
    const int bm = blockIdx.y * 128, bn = blockIdx.x * 64;
    const int t = threadIdx.x;
    const int tx = t & 15, ty = t >> 4;
    float acc[8][4] = {};
    for (int k0 = 0; k0 < K; k0 += 8) {
        if (ATRANS) {
            int k = t >> 5, c = (t & 31) << 2;
            *(float4*)&As[k][c] = *(const float4*)&A[(k0 + k) * M + bm + c];
        } else {
            int r = t >> 1, kq = (t & 1) << 2;
            float4 v = *(const float4*)&A[(bm + r) * K + k0 + kq];
            As[kq + 0][r] = v.x; As[kq + 1][r] = v.y; As[kq + 2][r] = v.z; As[kq + 3][r] = v.w;
        }
        if (t < 128) {
            int k = t >> 4, c = (t & 15) << 2;
            *(float4*)&Bs[k][c] = *(const float4*)&B[(k0 + k) * N + bn + c];
        }
        __syncthreads();
#pragma unroll
        for (int kk = 0; kk < 8; ++kk) {
            float a[8], bb[4];
            *(float4*)&a[0] = *(const float4*)&As[kk][ty * 8];
            *(float4*)&a[4] = *(const float4*)&As[kk][ty * 8 + 4];
            *(float4*)&bb[0] = *(const float4*)&Bs[kk][tx * 4];
#pragma unroll
            for (int i = 0; i < 8; ++i)
#pragma unroll
                for (int j = 0; j < 4; ++j)
                    acc[i][j] = fmaf(a[i], bb[j], acc[i][j]);
        }
        __syncthreads();
    }
#pragma unroll
    for (int i = 0; i < 8; ++i)
        *(float4*)&C[(bm + ty * 8 + i) * N + bn + tx * 4] = *(float4*)&acc[i][0];
}

// ---------------- launch ----------------

extern "C" void kernel_launch(void* const* d_in, const int* in_sizes, int n_in,
                              void* d_out, int out_size, void* d_ws, size_t ws_size,
                              hipStream_t stream) {
    const float* x1 = (const float*)d_in[0];
    const float* x2 = (const float*)d_in[1];
    const float* mask = (const float*)d_in[2];
    float* out = (float*)d_out;

    char* base = (char*)d_ws;
    // all sizes are multiples of 256B
    float* X2S = (float*)(base);                              // 128*2304*4       = 1,179,648
    float* MM  = (float*)(base + 1179648);                    // 2304*4           = 9,216
    float* RN  = (float*)(base + 1188864);                    // 2304*4           = 9,216
    float* buf1 = (float*)(base + 1198080);                   // 2304^2*4         = 21,233,664
    float* buf2 = (float*)(base + 22431744);                  // 2304^2*4
    float* RW  = (float*)(base + 43665408);                   // 2304*2048*4      = 18,874,368
    float* T   = (float*)(base + 62539776);                   // 2304*2048*4   -> end 81,414,144

    const int LL = Ls * Ls;
    const dim3 gridLL(Ls / 256, Ls);   // (9, 2304)

    for (int bb = 0; bb < 2; ++bb) {
        const float* x1b = x1 + (size_t)bb * Cc * Hh * Hh;
        const float* x2b = x2 + (size_t)bb * Cc * Hh * Hh;
        const float* maskb = mask + (size_t)bb * hs * hs;
        float* outb = out + (size_t)bb * Cc * Hh * Hh;

        subsample_k<<<(Cc * Ls + 255) / 256, 256, 0, stream>>>(x2b, X2S);
        mm_k<<<(Ls + 255) / 256, 256, 0, stream>>>(maskb, MM);

        // G = X^T X (Gram over channels): TN gemm, M=N=2304, K=128
        sgemm_k<true><<<dim3(Ls / 64, Ls / 128), 256, 0, stream>>>(X2S, X2S, buf1, Ls, Ls, Cc);

        taps_dx_k<<<gridLL, 256, 0, stream>>>(buf1, buf2);     // H
        taps_dy_k<<<gridLL, 256, 0, stream>>>(buf2, buf1);     // S
        rnorm_k<<<(Ls + 255) / 256, 256, 0, stream>>>(buf1, RN);
        fuse1_k<<<gridLL, 256, 0, stream>>>(buf1, RN, buf2);   // z1
        fuse2_k<<<gridLL, 256, 0, stream>>>(buf2, buf1);       // z2
        softmax_T_k<<<Ls, 256, 0, stream>>>(buf1, MM, buf2);   // A^T (p-major)

        gather_rw_k<<<(Ls * CK + 255) / 256, 256, 0, stream>>>(x1b, RW);

        // T = A^T (2304x2304) @ RW (2304x2048): NN gemm
        sgemm_k<false><<<dim3(CK / 64, Ls / 128), 256, 0, stream>>>(buf2, RW, T, Ls, CK, Ls);

        scatter_k<<<(Cc * Hh * Hh + 255) / 256, 256, 0, stream>>>(T, outb);
    }
    (void)in_sizes; (void)n_in; (void)out_size; (void)ws_size; (void)LL;
}

// Round 2
// 449.964 us; speedup vs baseline: 2.2826x; 2.2826x over previous
//
#include <hip/hip_runtime.h>
#include <hip/hip_bf16.h>

// Problem constants (ContextualAttention):
//  B=2, C=128, H=W=96, rate=2 -> h=w=48, L=2304, kernel=4, KSIZE=3, SCALE=10
#define Cc   128
#define Hh   96
#define hs   48
#define Ls   2304      // 48*48
#define CK   2048      // C*16

typedef __attribute__((ext_vector_type(8))) short short8;
typedef __attribute__((ext_vector_type(4))) float f32x4;

__device__ __forceinline__ unsigned short f2bf(float x) {
    unsigned int u = __float_as_uint(x);
    unsigned int r = (u + 0x7fff + ((u >> 16) & 1)) >> 16;   // RNE
    return (unsigned short)r;
}

#define GLOAD_LDS16(g, l) \
    __builtin_amdgcn_global_load_lds((__attribute__((address_space(1))) const void*)(g), \
                                     (__attribute__((address_space(3))) void*)(l), 16, 0, 0)

// ---------------- small kernels ----------------

__global__ __launch_bounds__(256) void subsample_k(const float* __restrict__ x2, float* __restrict__ X2S) {
    int idx = blockIdx.x * 256 + threadIdx.x;           // < 128*48*48
    if (idx >= Cc * Ls) return;
    int j = idx % hs, i = (idx / hs) % hs, c = idx / Ls;
    X2S[idx] = x2[c * (Hh * Hh) + (2 * i) * Hh + 2 * j];
}

__global__ __launch_bounds__(256) void mm_k(const float* __restrict__ mask, float* __restrict__ MM) {
    int l = blockIdx.x * 256 + threadIdx.x;
    if (l >= Ls) return;
    int ly = l / hs, lx = l % hs;
    float s = 0.f;
    for (int dy = -1; dy <= 1; ++dy)
        for (int dx = -1; dx <= 1; ++dx) {
            int yy = ly + dy, xx = lx + dx;
            if ((unsigned)yy < (unsigned)hs && (unsigned)xx < (unsigned)hs) s += mask[yy * hs + xx];
        }
    float m = s * (1.0f / 9.0f);
    MM[l] = (m == 0.0f) ? 1.0f : 0.0f;
}

// fused taps: S[i,j] = sum_{dy,dx} G[i+48dy+dx, j+48dy+dx] with pixel-space validity
__global__ __launch_bounds__(256) void taps9_k(const float* __restrict__ G, float* __restrict__ S) {
    int j = blockIdx.x * 256 + threadIdx.x;
    int i = blockIdx.y;
    int ix = i % hs, iy = i / hs, jx = j % hs, jy = j / hs;
    float s = 0.f;
#pragma unroll
    for (int dy = -1; dy <= 1; ++dy) {
        if ((unsigned)(iy + dy) >= (unsigned)hs || (unsigned)(jy + dy) >= (unsigned)hs) continue;
#pragma unroll
        for (int dx = -1; dx <= 1; ++dx) {
            if ((unsigned)(ix + dx) >= (unsigned)hs || (unsigned)(jx + dx) >= (unsigned)hs) continue;
            int off = 48 * dy + dx;
            s += G[(size_t)(i + off) * Ls + (j + off)];
        }
    }
    S[(size_t)i * Ls + j] = s;
}

__global__ __launch_bounds__(256) void rnorm_k(const float* __restrict__ S, float* __restrict__ RN) {
    int l = blockIdx.x * 256 + threadIdx.x;
    if (l >= Ls) return;
    RN[l] = 1.0f / fmaxf(sqrtf(S[(size_t)l * Ls + l]), 1e-4f);
}

// fused fuse2(fuse1): z2[i,j] = sum_{d2} sum_{d1} S[t(t(i)+d2)+d1, t(t(j)+d2)+d1] * RN[t(t(i)+d2)+d1]
// t(y*48+x) = x*48+y; d2 validity on flat t(i)+d2, d1 validity on flat row/col
__global__ __launch_bounds__(256) void fuse12_k(const float* __restrict__ S, const float* __restrict__ RN,
                                                float* __restrict__ Z) {
    int j = blockIdx.x * 256 + threadIdx.x;
    int i = blockIdx.y;
    int iy = i / hs, ix = i % hs; int ti = ix * hs + iy;
    int jy = j / hs, jx = j % hs; int tj = jx * hs + jy;
    float s = 0.f;
#pragma unroll
    for (int d2 = -1; d2 <= 1; ++d2) {
        int i2 = ti + d2, j2 = tj + d2;
        if ((unsigned)i2 >= (unsigned)Ls || (unsigned)j2 >= (unsigned)Ls) continue;
        int r = (i2 % hs) * hs + i2 / hs;
        int c = (j2 % hs) * hs + j2 / hs;
#pragma unroll
        for (int d1 = -1; d1 <= 1; ++d1) {
            int rr = r + d1, cc = c + d1;
            if ((unsigned)rr >= (unsigned)Ls || (unsigned)cc >= (unsigned)Ls) continue;
            s += S[(size_t)rr * Ls + cc] * RN[rr];
        }
    }
    Z[(size_t)i * Ls + j] = s;
}

// Softmax over l (rows) per column p; writes transposed bf16 result AT[p, l].
__global__ __launch_bounds__(256) void softmax_T_k(const float* __restrict__ Y, const float* __restrict__ MM,
                                                   unsigned short* __restrict__ AT) {
    const int p = blockIdx.x;
    const int t = threadIdx.x;
    float v[9];
    float mx = -3.4e38f;
#pragma unroll
    for (int i = 0; i < 9; ++i) {
        int l = i * 256 + t;
        v[i] = Y[(size_t)l * Ls + p] * MM[l] * 10.0f;
        mx = fmaxf(mx, v[i]);
    }
    for (int off = 32; off; off >>= 1) mx = fmaxf(mx, __shfl_xor(mx, off));
    __shared__ float sred[4];
    __shared__ float ssum[4];
    int wv = t >> 6;
    if ((t & 63) == 0) sred[wv] = mx;
    __syncthreads();
    mx = fmaxf(fmaxf(sred[0], sred[1]), fmaxf(sred[2], sred[3]));
    float e[9];
    float sum = 0.f;
#pragma unroll
    for (int i = 0; i < 9; ++i) { e[i] = expf(v[i] - mx); sum += e[i]; }
    for (int off = 32; off; off >>= 1) sum += __shfl_xor(sum, off);
    if ((t & 63) == 0) ssum[wv] = sum;
    __syncthreads();
    sum = ssum[0] + ssum[1] + ssum[2] + ssum[3];
    float rs = 1.0f / sum;
#pragma unroll
    for (int i = 0; i < 9; ++i) {
        int l = i * 256 + t;
        AT[(size_t)p * Ls + l] = f2bf(fmaxf(e[i] * rs * MM[l], 1e-8f));
    }
}

// raw_w^T gather (bf16, N-major K-contiguous): RWT[ck*L + l] = x1[c, 2ly+a-1, 2lx+b-1]
__global__ __launch_bounds__(256) void gather_rwT_k(const float* __restrict__ x1, unsigned short* __restrict__ RWT) {
    int l = blockIdx.x * 256 + threadIdx.x;   // < 2304
    int ck = blockIdx.y;                      // < 2048
    int c = ck >> 4, a = (ck >> 2) & 3, b2 = ck & 3;
    int ly = l / hs, lx = l % hs;
    int u = 2 * ly + a - 1, vv = 2 * lx + b2 - 1;
    float val = ((unsigned)u < (unsigned)Hh && (unsigned)vv < (unsigned)Hh) ? x1[c * (Hh * Hh) + u * Hh + vv] : 0.0f;
    RWT[(size_t)ck * Ls + l] = f2bf(val);
}

// out[c,Y,X] = 0.25 * sum over <=4 covering (i,j,a,b): T[(i*48+j)*2048 + c*16 + a*4 + b]
__global__ __launch_bounds__(256) void scatter_k(const float* __restrict__ T, float* __restrict__ out) {
    int idx = blockIdx.x * 256 + threadIdx.x;          // < 128*96*96
    if (idx >= Cc * Hh * Hh) return;
    int X = idx % Hh, Y = (idx / Hh) % Hh, c = idx / (Hh * Hh);
    int a0 = (Y + 1) & 1;
    int b0 = (X + 1) & 1;
    float s = 0.f;
#pragma unroll
    for (int ai = 0; ai < 2; ++ai) {
        int a = a0 + 2 * ai;
        int i = (Y + 1 - a) >> 1;
        if ((unsigned)i >= (unsigned)hs) continue;
#pragma unroll
        for (int bi = 0; bi < 2; ++bi) {
            int b2 = b0 + 2 * bi;
            int jj = (X + 1 - b2) >> 1;
            if ((unsigned)jj >= (unsigned)hs) continue;
            s += T[(size_t)(i * hs + jj) * CK + c * 16 + a * 4 + b2];
        }
    }
    out[idx] = 0.25f * s;
}

// ---------------- f32 GEMM (Gram only: must stay f32 — feeds exp(10*y)) ----------------
template <bool ATRANS>
__global__ __launch_bounds__(256) void sgemm_k(const float* __restrict__ A, const float* __restrict__ B,
                                               float* __restrict__ C, int M, int N, int K) {
    __shared__ float As[8][128];
    __shared__ float Bs[8][64];
    const int bm = blockIdx.y * 128, bn = blockIdx.x * 64;
    const int t = threadIdx.x;
    const int tx = t & 15, ty = t >> 4;
    float acc[8][4] = {};
    for (int k0 = 0; k0 < K; k0 += 8) {
        if (ATRANS) {
            int k = t >> 5, c = (t & 31) << 2;
            *(float4*)&As[k][c] = *(const float4*)&A[(size_t)(k0 + k) * M + bm + c];
        } else {
            int r = t >> 1, kq = (t & 1) << 2;
            float4 v = *(const float4*)&A[(size_t)(bm + r) * K + k0 + kq];
            As[kq + 0][r] = v.x; As[kq + 1][r] = v.y; As[kq + 2][r] = v.z; As[kq + 3][r] = v.w;
        }
        if (t < 128) {
            int k = t >> 4, c = (t & 15) << 2;
            *(float4*)&Bs[k][c] = *(const float4*)&B[(size_t)(k0 + k) * N + bn + c];
        }
        __syncthreads();
#pragma unroll
        for (int kk = 0; kk < 8; ++kk) {
            float a[8], bb[4];
            *(float4*)&a[0] = *(const float4*)&As[kk][ty * 8];
            *(float4*)&a[4] = *(const float4*)&As[kk][ty * 8 + 4];
            *(float4*)&bb[0] = *(const float4*)&Bs[kk][tx * 4];
#pragma unroll
            for (int i = 0; i < 8; ++i)
#pragma unroll
                for (int j = 0; j < 4; ++j)
                    acc[i][j] = fmaf(a[i], bb[j], acc[i][j]);
        }
        __syncthreads();
    }
#pragma unroll
    for (int i = 0; i < 8; ++i)
        *(float4*)&C[(size_t)(bm + ty * 8 + i) * N + bn + tx * 4] = *(float4*)&acc[i][0];
}

// ---------------- bf16 MFMA GEMM (deconv): C[M,N] = A[M,K] * B^T[N,K]^T ----------------
// A: bf16 M x K row-major (AT: p-major, l contiguous)
// Bt: bf16 N x K row-major (RWT: ck-major, l contiguous)
// C: f32 M x N. M=2304, N=2048, K=2304. Tile 128x128, BK=32, 4 waves.
__global__ __launch_bounds__(256) void mfma_gemm_k(const unsigned short* __restrict__ A,
                                                   const unsigned short* __restrict__ Bt,
                                                   float* __restrict__ C, int M, int N, int K) {
    __shared__ __align__(16) unsigned short Asm[128 * 32];
    __shared__ __align__(16) unsigned short Bsm[128 * 32];
    const int t = threadIdx.x;
    const int lane = t & 63, w = t >> 6;
    const int bm = blockIdx.y * 128, bn = blockIdx.x * 128;
    const int wr = w >> 1, wc = w & 1;

    // staging addresses: chunk q = 2w+i covers LDS bytes [q*1024, q*1024+1024)
    // lane writes LDS byte q*1024 + lane*16 -> row = q*16 + lane/4, kslot = lane%4 (8 bf16)
    const int rA = 32 * w + (lane >> 2);
    const int kA = (lane & 3) * 8;
    const unsigned short* gA0 = A + (size_t)(bm + rA) * K + kA;
    const unsigned short* gA1 = gA0 + (size_t)16 * K;
    const unsigned short* gB0 = Bt + (size_t)(bn + rA) * K + kA;
    const unsigned short* gB1 = gB0 + (size_t)16 * K;
    unsigned short* lA0 = &Asm[(2 * w) * 512];
    unsigned short* lA1 = &Asm[(2 * w + 1) * 512];
    unsigned short* lB0 = &Bsm[(2 * w) * 512];
    unsigned short* lB1 = &Bsm[(2 * w + 1) * 512];

    const int fr = lane & 15, fq = lane >> 4;
    f32x4 acc[4][4] = {};

    for (int k0 = 0; k0 < K; k0 += 32) {
        GLOAD_LDS16(gA0 + k0, lA0);
        GLOAD_LDS16(gA1 + k0, lA1);
        GLOAD_LDS16(gB0 + k0, lB0);
        GLOAD_LDS16(gB1 + k0, lB1);
        __syncthreads();
        short8 av[4], bv[4];
#pragma unroll
        for (int m = 0; m < 4; ++m)
            av[m] = *(const short8*)&Asm[(wr * 64 + m * 16 + fr) * 32 + fq * 8];
#pragma unroll
        for (int n = 0; n < 4; ++n)
            bv[n] = *(const short8*)&Bsm[(wc * 64 + n * 16 + fr) * 32 + fq * 8];
#pragma unroll
        for (int m = 0; m < 4; ++m)
#pragma unroll
            for (int n = 0; n < 4; ++n)
                acc[m][n] = __builtin_amdgcn_mfma_f32_16x16x32_bf16(av[m], bv[n], acc[m][n], 0, 0, 0);
        __syncthreads();
    }
    // C/D layout: col = lane&15, row = (lane>>4)*4 + reg
#pragma unroll
    for (int m = 0; m < 4; ++m) {
        int row0 = bm + wr * 64 + m * 16 + fq * 4;
#pragma unroll
        for (int n = 0; n < 4; ++n) {
            int col = bn + wc * 64 + n * 16 + fr;
#pragma unroll
            for (int r = 0; r < 4; ++r)
                C[(size_t)(row0 + r) * N + col] = acc[m][n][r];
        }
    }
}

// ---------------- launch ----------------

extern "C" void kernel_launch(void* const* d_in, const int* in_sizes, int n_in,
                              void* d_out, int out_size, void* d_ws, size_t ws_size,
                              hipStream_t stream) {
    const float* x1 = (const float*)d_in[0];
    const float* x2 = (const float*)d_in[1];
    const float* mask = (const float*)d_in[2];
    float* out = (float*)d_out;

    char* base = (char*)d_ws;
    float* X2S  = (float*)(base);                        // 1,179,648
    float* MM   = (float*)(base + 1179648);              // 9,216
    float* RN   = (float*)(base + 1188864);              // 9,216
    float* buf1 = (float*)(base + 1198080);              // 21,233,664  (G, then z2)
    float* buf2 = (float*)(base + 22431744);             // 21,233,664  (S, then T f32 18.9MB)
    unsigned short* ATb = (unsigned short*)(base + 43665408);  // 10,616,832 bf16
    unsigned short* RWT = (unsigned short*)(base + 54282240);  // 9,437,184 bf16 -> end 63,719,424
    float* T = buf2;

    const dim3 gridLL(Ls / 256, Ls);   // (9, 2304)

    for (int bb = 0; bb < 2; ++bb) {
        const float* x1b = x1 + (size_t)bb * Cc * Hh * Hh;
        const float* x2b = x2 + (size_t)bb * Cc * Hh * Hh;
        const float* maskb = mask + (size_t)bb * hs * hs;
        float* outb = out + (size_t)bb * Cc * Hh * Hh;

        subsample_k<<<(Cc * Ls + 255) / 256, 256, 0, stream>>>(x2b, X2S);
        mm_k<<<(Ls + 255) / 256, 256, 0, stream>>>(maskb, MM);

        // G = X^T X (Gram over channels): TN f32 gemm, M=N=2304, K=128
        sgemm_k<true><<<dim3(Ls / 64, Ls / 128), 256, 0, stream>>>(X2S, X2S, buf1, Ls, Ls, Cc);

        taps9_k<<<gridLL, 256, 0, stream>>>(buf1, buf2);       // S
        rnorm_k<<<(Ls + 255) / 256, 256, 0, stream>>>(buf2, RN);
        fuse12_k<<<gridLL, 256, 0, stream>>>(buf2, RN, buf1);  // z2
        softmax_T_k<<<Ls, 256, 0, stream>>>(buf1, MM, ATb);    // A^T bf16 (p-major)

        gather_rwT_k<<<dim3(Ls / 256, CK), 256, 0, stream>>>(x1b, RWT);

        // T = A^T (2304x2304) @ RW (2304x2048) via bf16 MFMA, B supplied as RWT (N x K)
        mfma_gemm_k<<<dim3(CK / 128, Ls / 128), 256, 0, stream>>>(ATb, RWT, T, Ls, CK, Ls);

        scatter_k<<<(Cc * Hh * Hh + 255) / 256, 256, 0, stream>>>(T, outb);
    }
    (void)in_sizes; (void)n_in; (void)out_size; (void)ws_size;
}

// Round 3
// 381.730 us; speedup vs baseline: 2.6907x; 1.1787x over previous
//
#include <hip/hip_runtime.h>
#include <hip/hip_bf16.h>

// Problem constants (ContextualAttention):
//  B=2, C=128, H=W=96, rate=2 -> h=w=48, L=2304, kernel=4, KSIZE=3, SCALE=10
#define Cc   128
#define Hh   96
#define hs   48
#define Ls   2304      // 48*48
#define CK   2048      // C*16
#define KG   384       // Gram split-K: [h|lo|h] / [h|h|lo]

typedef __attribute__((ext_vector_type(8))) short short8;
typedef __attribute__((ext_vector_type(4))) float f32x4;

__device__ __forceinline__ unsigned short f2bf(float x) {
    unsigned int u = __float_as_uint(x);
    unsigned int r = (u + 0x7fff + ((u >> 16) & 1)) >> 16;   // RNE
    return (unsigned short)r;
}

#define GLOAD_LDS16(g, l) \
    __builtin_amdgcn_global_load_lds((__attribute__((address_space(1))) const void*)(g), \
                                     (__attribute__((address_space(3))) void*)(l), 16, 0, 0)

// ---------------- small kernels ----------------

__global__ __launch_bounds__(256) void subsample_k(const float* __restrict__ x2, float* __restrict__ X2S) {
    int idx = blockIdx.x * 256 + threadIdx.x;           // < 128*48*48
    if (idx >= Cc * Ls) return;
    int j = idx % hs, i = (idx / hs) % hs, c = idx / Ls;
    X2S[idx] = x2[c * (Hh * Hh) + (2 * i) * Hh + 2 * j];
}

// X2S [c][l] f32 -> P,Q [l][384] bf16 (hi/lo split), via LDS transpose
__global__ __launch_bounds__(256) void transposePQ_k(const float* __restrict__ X2S,
                                                     unsigned short* __restrict__ P,
                                                     unsigned short* __restrict__ Q) {
    __shared__ float tile[64][65];
    const int c0 = blockIdx.x * 64;      // 0 or 64
    const int l0 = blockIdx.y * 64;      // 36 tiles
    const int t = threadIdx.x;
    const int lt = t & 63, cg = t >> 6;  // cg 0..3
#pragma unroll
    for (int cc = 0; cc < 16; ++cc) {
        int c = cg * 16 + cc;
        tile[lt][c] = X2S[(size_t)(c0 + c) * Ls + l0 + lt];
    }
    __syncthreads();
    const int lr = t >> 2, seg = t & 3;
    const int l = l0 + lr;
    short8 hv0, hv1, lv0, lv1;
#pragma unroll
    for (int k = 0; k < 8; ++k) {
        float x = tile[lr][seg * 16 + k];
        unsigned short h = f2bf(x);
        float hf = __uint_as_float((unsigned)h << 16);
        unsigned short lo = f2bf(x - hf);
        hv0[k] = (short)h; lv0[k] = (short)lo;
    }
#pragma unroll
    for (int k = 0; k < 8; ++k) {
        float x = tile[lr][seg * 16 + 8 + k];
        unsigned short h = f2bf(x);
        float hf = __uint_as_float((unsigned)h << 16);
        unsigned short lo = f2bf(x - hf);
        hv1[k] = (short)h; lv1[k] = (short)lo;
    }
    size_t rowp = (size_t)l * KG;
    int coff = c0 + seg * 16;
    *(short8*)&P[rowp + coff] = hv0;        *(short8*)&P[rowp + coff + 8] = hv1;
    *(short8*)&P[rowp + 128 + coff] = lv0;  *(short8*)&P[rowp + 128 + coff + 8] = lv1;
    *(short8*)&P[rowp + 256 + coff] = hv0;  *(short8*)&P[rowp + 256 + coff + 8] = hv1;
    *(short8*)&Q[rowp + coff] = hv0;        *(short8*)&Q[rowp + coff + 8] = hv1;
    *(short8*)&Q[rowp + 128 + coff] = hv0;  *(short8*)&Q[rowp + 128 + coff + 8] = hv1;
    *(short8*)&Q[rowp + 256 + coff] = lv0;  *(short8*)&Q[rowp + 256 + coff + 8] = lv1;
}

__global__ __launch_bounds__(256) void mm_k(const float* __restrict__ mask, float* __restrict__ MM) {
    int z = blockIdx.y;
    const float* mb = mask + (size_t)z * hs * hs;
    float* MMb = MM + (size_t)z * Ls;
    int l = blockIdx.x * 256 + threadIdx.x;
    if (l >= Ls) return;
    int ly = l / hs, lx = l % hs;
    float s = 0.f;
    for (int dy = -1; dy <= 1; ++dy)
        for (int dx = -1; dx <= 1; ++dx) {
            int yy = ly + dy, xx = lx + dx;
            if ((unsigned)yy < (unsigned)hs && (unsigned)xx < (unsigned)hs) s += mb[yy * hs + xx];
        }
    float m = s * (1.0f / 9.0f);
    MMb[l] = (m == 0.0f) ? 1.0f : 0.0f;
}

// fused taps + rnorm: S[i,j] = sum_{dy,dx} G[i+48dy+dx, j+48dy+dx]; RN[i] from diagonal
__global__ __launch_bounds__(256) void taps9rn_k(const float* __restrict__ G, float* __restrict__ S,
                                                 float* __restrict__ RN) {
    int j = blockIdx.x * 256 + threadIdx.x;
    int i = blockIdx.y;
    int ix = i % hs, iy = i / hs, jx = j % hs, jy = j / hs;
    float s = 0.f;
#pragma unroll
    for (int dy = -1; dy <= 1; ++dy) {
        if ((unsigned)(iy + dy) >= (unsigned)hs || (unsigned)(jy + dy) >= (unsigned)hs) continue;
#pragma unroll
        for (int dx = -1; dx <= 1; ++dx) {
            if ((unsigned)(ix + dx) >= (unsigned)hs || (unsigned)(jx + dx) >= (unsigned)hs) continue;
            int off = 48 * dy + dx;
            s += G[(size_t)(i + off) * Ls + (j + off)];
        }
    }
    S[(size_t)i * Ls + j] = s;
    if (j == i) RN[i] = 1.0f / fmaxf(sqrtf(s), 1e-4f);
}

// fused fuse2(fuse1) with transposed output: ZT[j][i] = z2[i][j]
__global__ __launch_bounds__(256) void fuse12T_k(const float* __restrict__ S, const float* __restrict__ RN,
                                                 float* __restrict__ ZT) {
    __shared__ float tile[64][65];
    const int i0 = blockIdx.y * 64, j0 = blockIdx.x * 64;
    const int t = threadIdx.x;
    const int tj = t & 63, tib = t >> 6;
    const int j = j0 + tj;
    const int jy = j / hs, jx = j % hs;
    const int tjf = jx * hs + jy;
#pragma unroll
    for (int k = 0; k < 16; ++k) {
        int ti = tib * 16 + k;
        int i = i0 + ti;
        int iy = i / hs, ix = i % hs;
        int tif = ix * hs + iy;
        float s = 0.f;
#pragma unroll
        for (int d2 = -1; d2 <= 1; ++d2) {
            int i2 = tif + d2, j2 = tjf + d2;
            if ((unsigned)i2 >= (unsigned)Ls || (unsigned)j2 >= (unsigned)Ls) continue;
            int r = (i2 % hs) * hs + i2 / hs;
            int c = (j2 % hs) * hs + j2 / hs;
#pragma unroll
            for (int d1 = -1; d1 <= 1; ++d1) {
                int rr = r + d1, cc = c + d1;
                if ((unsigned)rr >= (unsigned)Ls || (unsigned)cc >= (unsigned)Ls) continue;
                s += S[(size_t)rr * Ls + cc] * RN[rr];
            }
        }
        tile[ti][tj] = s;
    }
    __syncthreads();
    const int r = t >> 2, cs = (t & 3) * 16;
    float vbuf[16];
#pragma unroll
    for (int k = 0; k < 16; ++k) vbuf[k] = tile[cs + k][r];
    float* dst = &ZT[(size_t)(j0 + r) * Ls + i0 + cs];
#pragma unroll
    for (int k = 0; k < 4; ++k)
        *(float4*)&dst[k * 4] = *(float4*)&vbuf[k * 4];
}

// row softmax over ZT[p][l] (coalesced), writes bf16 AT[p][l]
__global__ __launch_bounds__(256) void softmax_row_k(const float* __restrict__ ZT, const float* __restrict__ MM,
                                                     unsigned short* __restrict__ AT) {
    const int w = threadIdx.x >> 6, lane = threadIdx.x & 63;
    const int p = blockIdx.x * 4 + w;
    const float* row = ZT + (size_t)p * Ls;
    float v[36];
    float mx = -3.4e38f;
#pragma unroll
    for (int k = 0; k < 9; ++k) {
        const float4 z = *(const float4*)&row[k * 256 + lane * 4];
        const float4 m = *(const float4*)&MM[k * 256 + lane * 4];
        v[4 * k + 0] = z.x * m.x * 10.f;
        v[4 * k + 1] = z.y * m.y * 10.f;
        v[4 * k + 2] = z.z * m.z * 10.f;
        v[4 * k + 3] = z.w * m.w * 10.f;
        mx = fmaxf(mx, fmaxf(fmaxf(v[4 * k], v[4 * k + 1]), fmaxf(v[4 * k + 2], v[4 * k + 3])));
    }
#pragma unroll
    for (int off = 32; off; off >>= 1) mx = fmaxf(mx, __shfl_xor(mx, off));
    float sum = 0.f;
#pragma unroll
    for (int kk = 0; kk < 36; ++kk) { v[kk] = expf(v[kk] - mx); sum += v[kk]; }
#pragma unroll
    for (int off = 32; off; off >>= 1) sum += __shfl_xor(sum, off);
    const float rs = 1.0f / sum;
#pragma unroll
    for (int k = 0; k < 9; ++k) {
        const float4 m = *(const float4*)&MM[k * 256 + lane * 4];
        ushort4 o;
        o.x = f2bf(fmaxf(v[4 * k + 0] * rs * m.x, 1e-8f));
        o.y = f2bf(fmaxf(v[4 * k + 1] * rs * m.y, 1e-8f));
        o.z = f2bf(fmaxf(v[4 * k + 2] * rs * m.z, 1e-8f));
        o.w = f2bf(fmaxf(v[4 * k + 3] * rs * m.w, 1e-8f));
        *(ushort4*)&AT[(size_t)p * Ls + k * 256 + lane * 4] = o;
    }
}

// raw_w^T gather (bf16, N-major K-contiguous), z-batched
__global__ __launch_bounds__(256) void gather_rwT_k(const float* __restrict__ x1, unsigned short* __restrict__ RWT) {
    const int z = blockIdx.z;
    const float* x1b = x1 + (size_t)z * Cc * Hh * Hh;
    unsigned short* R = RWT + (size_t)z * CK * Ls;
    int l = blockIdx.x * 256 + threadIdx.x;   // < 2304
    int ck = blockIdx.y;                      // < 2048
    int c = ck >> 4, a = (ck >> 2) & 3, b2 = ck & 3;
    int ly = l / hs, lx = l % hs;
    int u = 2 * ly + a - 1, vv = 2 * lx + b2 - 1;
    float val = ((unsigned)u < (unsigned)Hh && (unsigned)vv < (unsigned)Hh) ? x1b[c * (Hh * Hh) + u * Hh + vv] : 0.0f;
    R[(size_t)ck * Ls + l] = f2bf(val);
}

// out[c,Y,X] = 0.25 * sum over <=4 covering (i,j,a,b): T[(i*48+j)*2048 + c*16 + a*4 + b]; z-batched
__global__ __launch_bounds__(256) void scatter_k(const float* __restrict__ T, float* __restrict__ out) {
    const int z = blockIdx.z;
    const float* Tb = T + (size_t)z * Ls * CK;
    float* outb = out + (size_t)z * Cc * Hh * Hh;
    int idx = blockIdx.x * 256 + threadIdx.x;          // < 128*96*96
    if (idx >= Cc * Hh * Hh) return;
    int X = idx % Hh, Y = (idx / Hh) % Hh, c = idx / (Hh * Hh);
    int a0 = (Y + 1) & 1;
    int b0 = (X + 1) & 1;
    float s = 0.f;
#pragma unroll
    for (int ai = 0; ai < 2; ++ai) {
        int a = a0 + 2 * ai;
        int i = (Y + 1 - a) >> 1;
        if ((unsigned)i >= (unsigned)hs) continue;
#pragma unroll
        for (int bi = 0; bi < 2; ++bi) {
            int b2 = b0 + 2 * bi;
            int jj = (X + 1 - b2) >> 1;
            if ((unsigned)jj >= (unsigned)hs) continue;
            s += Tb[(size_t)(i * hs + jj) * CK + c * 16 + a * 4 + b2];
        }
    }
    outb[idx] = 0.25f * s;
}

// ---------------- bf16 MFMA GEMM: C[M,N] = A[M,K] * Bt[N,K]^T, z-batched, XCD-swizzled ----------------
__global__ __launch_bounds__(256) void mfma_gemm_k(const unsigned short* __restrict__ A,
                                                   const unsigned short* __restrict__ Bt,
                                                   float* __restrict__ C, int M, int N, int K,
                                                   long long sA, long long sB, long long sC) {
    A  += (size_t)blockIdx.z * sA;
    Bt += (size_t)blockIdx.z * sB;
    C  += (size_t)blockIdx.z * sC;

    // bijective XCD-aware swizzle over (x,y)
    const int nb = gridDim.x * gridDim.y;
    const int flat = blockIdx.y * gridDim.x + blockIdx.x;
    const int q = nb >> 3, r = nb & 7;
    const int xcd = flat & 7, sidx = flat >> 3;
    const int wg = (xcd < r ? xcd * (q + 1) : r * (q + 1) + (xcd - r) * q) + sidx;
    const int bm = (wg / gridDim.x) * 128, bn = (wg % gridDim.x) * 128;

    __shared__ __align__(16) unsigned short Asm[128 * 32];
    __shared__ __align__(16) unsigned short Bsm[128 * 32];
    const int t = threadIdx.x;
    const int lane = t & 63, w = t >> 6;
    const int wr = w >> 1, wc = w & 1;

    const int rA = 32 * w + (lane >> 2);
    const int kA = (lane & 3) * 8;
    const unsigned short* gA0 = A + (size_t)(bm + rA) * K + kA;
    const unsigned short* gA1 = gA0 + (size_t)16 * K;
    const unsigned short* gB0 = Bt + (size_t)(bn + rA) * K + kA;
    const unsigned short* gB1 = gB0 + (size_t)16 * K;
    unsigned short* lA0 = &Asm[(2 * w) * 512];
    unsigned short* lA1 = &Asm[(2 * w + 1) * 512];
    unsigned short* lB0 = &Bsm[(2 * w) * 512];
    unsigned short* lB1 = &Bsm[(2 * w + 1) * 512];

    const int fr = lane & 15, fq = lane >> 4;
    f32x4 acc[4][4] = {};

    for (int k0 = 0; k0 < K; k0 += 32) {
        GLOAD_LDS16(gA0 + k0, lA0);
        GLOAD_LDS16(gA1 + k0, lA1);
        GLOAD_LDS16(gB0 + k0, lB0);
        GLOAD_LDS16(gB1 + k0, lB1);
        __syncthreads();
        short8 av[4], bv[4];
#pragma unroll
        for (int m = 0; m < 4; ++m)
            av[m] = *(const short8*)&Asm[(wr * 64 + m * 16 + fr) * 32 + fq * 8];
#pragma unroll
        for (int n = 0; n < 4; ++n)
            bv[n] = *(const short8*)&Bsm[(wc * 64 + n * 16 + fr) * 32 + fq * 8];
#pragma unroll
        for (int m = 0; m < 4; ++m)
#pragma unroll
            for (int n = 0; n < 4; ++n)
                acc[m][n] = __builtin_amdgcn_mfma_f32_16x16x32_bf16(av[m], bv[n], acc[m][n], 0, 0, 0);
        __syncthreads();
    }
#pragma unroll
    for (int m = 0; m < 4; ++m) {
        int row0 = bm + wr * 64 + m * 16 + fq * 4;
#pragma unroll
        for (int n = 0; n < 4; ++n) {
            int col = bn + wc * 64 + n * 16 + fr;
#pragma unroll
            for (int rr = 0; rr < 4; ++rr)
                C[(size_t)(row0 + rr) * N + col] = acc[m][n][rr];
        }
    }
}

// ---------------- launch ----------------

extern "C" void kernel_launch(void* const* d_in, const int* in_sizes, int n_in,
                              void* d_out, int out_size, void* d_ws, size_t ws_size,
                              hipStream_t stream) {
    const float* x1 = (const float*)d_in[0];
    const float* x2 = (const float*)d_in[1];
    const float* mask = (const float*)d_in[2];
    float* out = (float*)d_out;

    char* base = (char*)d_ws;
    float* MM2  = (float*)(base);                         // 18,432
    float* RN   = (float*)(base + 18432);                 // 9,216
    float* X2S  = (float*)(base + 27648);                 // 1,179,648
    unsigned short* P = (unsigned short*)(base + 1207296);   // 1,769,472
    unsigned short* Q = (unsigned short*)(base + 2976768);   // 1,769,472
    float* bufG = (float*)(base + 4746240);               // 21,233,664 (G, then ZT)
    float* bufS = (float*)(base + 25979904);              // 21,233,664 (S)
    unsigned short* ATb2 = (unsigned short*)(base + 47213568); // 21,233,664 (both samples)
    unsigned short* RWT2 = (unsigned short*)(base + 68447232); // 18,874,368 (both samples)
    float* T2 = (float*)base;                             // 37,748,736 overlay (per-sample region dead)

    const size_t LsLs = (size_t)Ls * Ls;

    mm_k<<<dim3(Ls / 256, 2), 256, 0, stream>>>(mask, MM2);
    gather_rwT_k<<<dim3(Ls / 256, CK, 2), 256, 0, stream>>>(x1, RWT2);

    for (int bb = 0; bb < 2; ++bb) {
        const float* x2b = x2 + (size_t)bb * Cc * Hh * Hh;

        subsample_k<<<(Cc * Ls + 255) / 256, 256, 0, stream>>>(x2b, X2S);
        transposePQ_k<<<dim3(2, Ls / 64), 256, 0, stream>>>(X2S, P, Q);

        // G = split-bf16 Gram: M=N=2304, K=384
        mfma_gemm_k<<<dim3(Ls / 128, Ls / 128, 1), 256, 0, stream>>>(P, Q, bufG, Ls, Ls, KG, 0, 0, 0);

        taps9rn_k<<<dim3(Ls / 256, Ls), 256, 0, stream>>>(bufG, bufS, RN);
        fuse12T_k<<<dim3(Ls / 64, Ls / 64), 256, 0, stream>>>(bufS, RN, bufG);   // ZT into bufG
        softmax_row_k<<<Ls / 4, 256, 0, stream>>>(bufG, MM2 + (size_t)bb * Ls,
                                                  ATb2 + (size_t)bb * LsLs);
    }

    // batched deconv GEMM: T = A^T @ RW for both samples
    mfma_gemm_k<<<dim3(CK / 128, Ls / 128, 2), 256, 0, stream>>>(
        ATb2, RWT2, T2, Ls, CK, Ls,
        (long long)LsLs, (long long)CK * Ls, (long long)Ls * CK);

    scatter_k<<<dim3((Cc * Hh * Hh + 255) / 256, 1, 2), 256, 0, stream>>>(T2, out);

    (void)in_sizes; (void)n_in; (void)out_size; (void)ws_size;
}

// Round 4
// 357.949 us; speedup vs baseline: 2.8694x; 1.0664x over previous
//
#include <hip/hip_runtime.h>
#include <hip/hip_bf16.h>

// Problem constants (ContextualAttention):
//  B=2, C=128, H=W=96, rate=2 -> h=w=48, L=2304, kernel=4, KSIZE=3, SCALE=10
#define Cc   128
#define Hh   96
#define hs   48
#define Ls   2304      // 48*48
#define CK   2048      // C*16
#define KG   384       // Gram split-K: [h|lo|h] / [h|h|lo]

typedef __attribute__((ext_vector_type(8))) short short8;
typedef __attribute__((ext_vector_type(4))) float f32x4;

__device__ __forceinline__ unsigned short f2bf(float x) {
    unsigned int u = __float_as_uint(x);
    unsigned int r = (u + 0x7fff + ((u >> 16) & 1)) >> 16;   // RNE
    return (unsigned short)r;
}

#define GLOAD_LDS16(g, l) \
    __builtin_amdgcn_global_load_lds((__attribute__((address_space(1))) const void*)(g), \
                                     (__attribute__((address_space(3))) void*)(l), 16, 0, 0)

// ---------------- small kernels ----------------

// fused subsample + transpose + bf16 hi/lo split: x2 -> P,Q [l][384]
__global__ __launch_bounds__(256) void transposePQ_k(const float* __restrict__ x2,
                                                     unsigned short* __restrict__ P,
                                                     unsigned short* __restrict__ Q,
                                                     long long sPQ, int z0) {
    const int z = z0 + blockIdx.z;
    const float* x2b = x2 + (size_t)z * Cc * Hh * Hh;
    unsigned short* Pb = P + (size_t)blockIdx.z * sPQ;
    unsigned short* Qb = Q + (size_t)blockIdx.z * sPQ;
    __shared__ float tile[64][65];
    const int c0 = blockIdx.x * 64;      // 0 or 64
    const int l0 = blockIdx.y * 64;      // 36 tiles
    const int t = threadIdx.x;
    const int lt = t & 63, cg = t >> 6;  // cg 0..3
    const int l = l0 + lt;
    const int iy = l / hs, jx = l % hs;
    const int srcoff = iy * (2 * Hh) + 2 * jx;
#pragma unroll
    for (int cc = 0; cc < 16; ++cc) {
        int c = cg * 16 + cc;
        tile[lt][c] = x2b[(size_t)(c0 + c) * (Hh * Hh) + srcoff];
    }
    __syncthreads();
    const int lr = t >> 2, seg = t & 3;
    const int lw = l0 + lr;
    short8 hv0, hv1, lv0, lv1;
#pragma unroll
    for (int k = 0; k < 8; ++k) {
        float x = tile[lr][seg * 16 + k];
        unsigned short h = f2bf(x);
        float hf = __uint_as_float((unsigned)h << 16);
        unsigned short lo = f2bf(x - hf);
        hv0[k] = (short)h; lv0[k] = (short)lo;
    }
#pragma unroll
    for (int k = 0; k < 8; ++k) {
        float x = tile[lr][seg * 16 + 8 + k];
        unsigned short h = f2bf(x);
        float hf = __uint_as_float((unsigned)h << 16);
        unsigned short lo = f2bf(x - hf);
        hv1[k] = (short)h; lv1[k] = (short)lo;
    }
    size_t rowp = (size_t)lw * KG;
    int coff = c0 + seg * 16;
    *(short8*)&Pb[rowp + coff] = hv0;        *(short8*)&Pb[rowp + coff + 8] = hv1;
    *(short8*)&Pb[rowp + 128 + coff] = lv0;  *(short8*)&Pb[rowp + 128 + coff + 8] = lv1;
    *(short8*)&Pb[rowp + 256 + coff] = hv0;  *(short8*)&Pb[rowp + 256 + coff + 8] = hv1;
    *(short8*)&Qb[rowp + coff] = hv0;        *(short8*)&Qb[rowp + coff + 8] = hv1;
    *(short8*)&Qb[rowp + 128 + coff] = hv0;  *(short8*)&Qb[rowp + 128 + coff + 8] = hv1;
    *(short8*)&Qb[rowp + 256 + coff] = lv0;  *(short8*)&Qb[rowp + 256 + coff + 8] = lv1;
}

__global__ __launch_bounds__(256) void mm_k(const float* __restrict__ mask, float* __restrict__ MM) {
    int z = blockIdx.y;
    const float* mb = mask + (size_t)z * hs * hs;
    float* MMb = MM + (size_t)z * Ls;
    int l = blockIdx.x * 256 + threadIdx.x;
    if (l >= Ls) return;
    int ly = l / hs, lx = l % hs;
    float s = 0.f;
    for (int dy = -1; dy <= 1; ++dy)
        for (int dx = -1; dx <= 1; ++dx) {
            int yy = ly + dy, xx = lx + dx;
            if ((unsigned)yy < (unsigned)hs && (unsigned)xx < (unsigned)hs) s += mb[yy * hs + xx];
        }
    float m = s * (1.0f / 9.0f);
    MMb[l] = (m == 0.0f) ? 1.0f : 0.0f;
}

// fused taps + rnorm: S[i,j] = sum_{dy,dx} G[i+48dy+dx, j+48dy+dx]; RN[i] from diagonal
__global__ __launch_bounds__(256) void taps9rn_k(const float* __restrict__ G, float* __restrict__ S,
                                                 float* __restrict__ RN, long long zsG, long long zsS, int z0) {
    const float* Gb = G + (size_t)blockIdx.z * zsG;
    float* Sb = S + (size_t)blockIdx.z * zsS;
    float* RNb = RN + (size_t)(z0 + blockIdx.z) * Ls;
    int j = blockIdx.x * 256 + threadIdx.x;
    int i = blockIdx.y;
    int ix = i % hs, iy = i / hs, jx = j % hs, jy = j / hs;
    float s = 0.f;
#pragma unroll
    for (int dy = -1; dy <= 1; ++dy) {
        if ((unsigned)(iy + dy) >= (unsigned)hs || (unsigned)(jy + dy) >= (unsigned)hs) continue;
#pragma unroll
        for (int dx = -1; dx <= 1; ++dx) {
            if ((unsigned)(ix + dx) >= (unsigned)hs || (unsigned)(jx + dx) >= (unsigned)hs) continue;
            int off = 48 * dy + dx;
            s += Gb[(size_t)(i + off) * Ls + (j + off)];
        }
    }
    Sb[(size_t)i * Ls + j] = s;
    if (j == i) RNb[i] = 1.0f / fmaxf(sqrtf(s), 1e-4f);
}

// fused fuse2(fuse1) with transposed output: ZT[j][i] = z2[i][j]
__global__ __launch_bounds__(256) void fuse12T_k(const float* __restrict__ S, const float* __restrict__ RN,
                                                 float* __restrict__ ZT, long long zsS, long long zsZT, int z0) {
    const float* Sb = S + (size_t)blockIdx.z * zsS;
    float* ZTb = ZT + (size_t)blockIdx.z * zsZT;
    const float* RNb = RN + (size_t)(z0 + blockIdx.z) * Ls;
    __shared__ float tile[64][65];
    const int i0 = blockIdx.y * 64, j0 = blockIdx.x * 64;
    const int t = threadIdx.x;
    const int tj = t & 63, tib = t >> 6;
    const int j = j0 + tj;
    const int jy = j / hs, jx = j % hs;
    const int tjf = jx * hs + jy;
#pragma unroll
    for (int k = 0; k < 16; ++k) {
        int ti = tib * 16 + k;
        int i = i0 + ti;
        int iy = i / hs, ix = i % hs;
        int tif = ix * hs + iy;
        float s = 0.f;
#pragma unroll
        for (int d2 = -1; d2 <= 1; ++d2) {
            int i2 = tif + d2, j2 = tjf + d2;
            if ((unsigned)i2 >= (unsigned)Ls || (unsigned)j2 >= (unsigned)Ls) continue;
            int r = (i2 % hs) * hs + i2 / hs;
            int c = (j2 % hs) * hs + j2 / hs;
#pragma unroll
            for (int d1 = -1; d1 <= 1; ++d1) {
                int rr = r + d1, cc = c + d1;
                if ((unsigned)rr >= (unsigned)Ls || (unsigned)cc >= (unsigned)Ls) continue;
                s += Sb[(size_t)rr * Ls + cc] * RNb[rr];
            }
        }
        tile[ti][tj] = s;
    }
    __syncthreads();
    const int r = t >> 2, cs = (t & 3) * 16;
    float vbuf[16];
#pragma unroll
    for (int k = 0; k < 16; ++k) vbuf[k] = tile[cs + k][r];
    float* dst = &ZTb[(size_t)(j0 + r) * Ls + i0 + cs];
#pragma unroll
    for (int k = 0; k < 4; ++k)
        *(float4*)&dst[k * 4] = *(float4*)&vbuf[k * 4];
}

// row softmax over ZT[p][l] (coalesced), writes bf16 AT[p][l]
__global__ __launch_bounds__(256) void softmax_row_k(const float* __restrict__ ZT, const float* __restrict__ MM,
                                                     unsigned short* __restrict__ AT, long long zsZT, int z0) {
    const int z = z0 + blockIdx.z;
    const float* ZTb = ZT + (size_t)blockIdx.z * zsZT;
    const float* MMb = MM + (size_t)z * Ls;
    unsigned short* ATb = AT + (size_t)z * Ls * Ls;
    const int w = threadIdx.x >> 6, lane = threadIdx.x & 63;
    const int p = blockIdx.x * 4 + w;
    const float* row = ZTb + (size_t)p * Ls;
    float v[36];
    float mx = -3.4e38f;
#pragma unroll
    for (int k = 0; k < 9; ++k) {
        const float4 zv = *(const float4*)&row[k * 256 + lane * 4];
        const float4 m = *(const float4*)&MMb[k * 256 + lane * 4];
        v[4 * k + 0] = zv.x * m.x * 10.f;
        v[4 * k + 1] = zv.y * m.y * 10.f;
        v[4 * k + 2] = zv.z * m.z * 10.f;
        v[4 * k + 3] = zv.w * m.w * 10.f;
        mx = fmaxf(mx, fmaxf(fmaxf(v[4 * k], v[4 * k + 1]), fmaxf(v[4 * k + 2], v[4 * k + 3])));
    }
#pragma unroll
    for (int off = 32; off; off >>= 1) mx = fmaxf(mx, __shfl_xor(mx, off));
    float sum = 0.f;
#pragma unroll
    for (int kk = 0; kk < 36; ++kk) { v[kk] = expf(v[kk] - mx); sum += v[kk]; }
#pragma unroll
    for (int off = 32; off; off >>= 1) sum += __shfl_xor(sum, off);
    const float rs = 1.0f / sum;
#pragma unroll
    for (int k = 0; k < 9; ++k) {
        const float4 m = *(const float4*)&MMb[k * 256 + lane * 4];
        ushort4 o;
        o.x = f2bf(fmaxf(v[4 * k + 0] * rs * m.x, 1e-8f));
        o.y = f2bf(fmaxf(v[4 * k + 1] * rs * m.y, 1e-8f));
        o.z = f2bf(fmaxf(v[4 * k + 2] * rs * m.z, 1e-8f));
        o.w = f2bf(fmaxf(v[4 * k + 3] * rs * m.w, 1e-8f));
        *(ushort4*)&ATb[(size_t)p * Ls + k * 256 + lane * 4] = o;
    }
}

// raw_w^T gather (bf16, N-major K-contiguous), z-batched
__global__ __launch_bounds__(256) void gather_rwT_k(const float* __restrict__ x1, unsigned short* __restrict__ RWT) {
    const int z = blockIdx.z;
    const float* x1b = x1 + (size_t)z * Cc * Hh * Hh;
    unsigned short* R = RWT + (size_t)z * CK * Ls;
    int l = blockIdx.x * 256 + threadIdx.x;   // < 2304
    int ck = blockIdx.y;                      // < 2048
    int c = ck >> 4, a = (ck >> 2) & 3, b2 = ck & 3;
    int ly = l / hs, lx = l % hs;
    int u = 2 * ly + a - 1, vv = 2 * lx + b2 - 1;
    float val = ((unsigned)u < (unsigned)Hh && (unsigned)vv < (unsigned)Hh) ? x1b[c * (Hh * Hh) + u * Hh + vv] : 0.0f;
    R[(size_t)ck * Ls + l] = f2bf(val);
}

// per-channel LDS-accumulated scatter: block = (channel, z)
__global__ __launch_bounds__(256) void scatter2_k(const float* __restrict__ T, float* __restrict__ out) {
    const int z = blockIdx.z;
    const int c = blockIdx.x;
    const float* Tb = T + (size_t)z * Ls * CK;
    float* outb = out + (size_t)z * Cc * Hh * Hh + (size_t)c * Hh * Hh;
    __shared__ float o[Hh * Hh];
    const int t = threadIdx.x;
    for (int i = t; i < Hh * Hh; i += 256) o[i] = 0.f;
    __syncthreads();
#pragma unroll
    for (int rep = 0; rep < 9; ++rep) {
        int p = rep * 256 + t;                 // 0..2303
        int i = p / hs, jj = p % hs;
        const float4* tp = (const float4*)&Tb[(size_t)p * CK + c * 16];
        float4 va = tp[0], vb = tp[1], vc = tp[2], vd = tp[3];
        float vals[16] = {va.x, va.y, va.z, va.w, vb.x, vb.y, vb.z, vb.w,
                          vc.x, vc.y, vc.z, vc.w, vd.x, vd.y, vd.z, vd.w};
#pragma unroll
        for (int a = 0; a < 4; ++a) {
            int Y = 2 * i + a - 1;
            if ((unsigned)Y >= (unsigned)Hh) continue;
#pragma unroll
            for (int b2 = 0; b2 < 4; ++b2) {
                int X = 2 * jj + b2 - 1;
                if ((unsigned)X >= (unsigned)Hh) continue;
                atomicAdd(&o[Y * Hh + X], vals[a * 4 + b2]);
            }
        }
    }
    __syncthreads();
    for (int i = t; i < Hh * Hh; i += 256) outb[i] = 0.25f * o[i];
}

// ---------------- bf16 MFMA GEMM: C[M,N] = A[M,K] * Bt[N,K]^T, z-batched ----------------
// supertile=1 requires grid exactly (16,18): 4x3-block supertiles for L2 reuse.
__global__ __launch_bounds__(256) void mfma_gemm_k(const unsigned short* __restrict__ A,
                                                   const unsigned short* __restrict__ Bt,
                                                   float* __restrict__ C, int M, int N, int K,
                                                   long long sA, long long sB, long long sC,
                                                   int supertile) {
    A  += (size_t)blockIdx.z * sA;
    Bt += (size_t)blockIdx.z * sB;
    C  += (size_t)blockIdx.z * sC;

    // bijective XCD-aware remap over (x,y)
    const int nb = gridDim.x * gridDim.y;
    const int flat = blockIdx.y * gridDim.x + blockIdx.x;
    const int q = nb >> 3, r = nb & 7;
    const int xcd = flat & 7, sidx = flat >> 3;
    const int wg = (xcd < r ? xcd * (q + 1) : r * (q + 1) + (xcd - r) * q) + sidx;
    int bm, bn;
    if (supertile) {
        // 24 supertiles of 4(n) x 3(m) blocks; working set 4*0.52+3*0.59 MB <= L2
        int st = wg / 12, tt = wg % 12;
        int stn = st & 3, stm = st >> 2;     // 4 x 6 supertile grid
        int tn = tt & 3, tm = tt >> 2;       // 4(n) x 3(m) within
        bn = (stn * 4 + tn) * 128;
        bm = (stm * 3 + tm) * 128;
    } else {
        bm = (wg / gridDim.x) * 128;
        bn = (wg % gridDim.x) * 128;
    }

    __shared__ __align__(16) unsigned short Asm[128 * 32];
    __shared__ __align__(16) unsigned short Bsm[128 * 32];
    const int t = threadIdx.x;
    const int lane = t & 63, w = t >> 6;
    const int wr = w >> 1, wc = w & 1;

    const int rA = 32 * w + (lane >> 2);
    const int kA = (lane & 3) * 8;
    const unsigned short* gA0 = A + (size_t)(bm + rA) * K + kA;
    const unsigned short* gA1 = gA0 + (size_t)16 * K;
    const unsigned short* gB0 = Bt + (size_t)(bn + rA) * K + kA;
    const unsigned short* gB1 = gB0 + (size_t)16 * K;
    unsigned short* lA0 = &Asm[(2 * w) * 512];
    unsigned short* lA1 = &Asm[(2 * w + 1) * 512];
    unsigned short* lB0 = &Bsm[(2 * w) * 512];
    unsigned short* lB1 = &Bsm[(2 * w + 1) * 512];

    const int fr = lane & 15, fq = lane >> 4;
    f32x4 acc[4][4] = {};

    for (int k0 = 0; k0 < K; k0 += 32) {
        GLOAD_LDS16(gA0 + k0, lA0);
        GLOAD_LDS16(gA1 + k0, lA1);
        GLOAD_LDS16(gB0 + k0, lB0);
        GLOAD_LDS16(gB1 + k0, lB1);
        __syncthreads();
        short8 av[4], bv[4];
#pragma unroll
        for (int m = 0; m < 4; ++m)
            av[m] = *(const short8*)&Asm[(wr * 64 + m * 16 + fr) * 32 + fq * 8];
#pragma unroll
        for (int n = 0; n < 4; ++n)
            bv[n] = *(const short8*)&Bsm[(wc * 64 + n * 16 + fr) * 32 + fq * 8];
#pragma unroll
        for (int m = 0; m < 4; ++m)
#pragma unroll
            for (int n = 0; n < 4; ++n)
                acc[m][n] = __builtin_amdgcn_mfma_f32_16x16x32_bf16(av[m], bv[n], acc[m][n], 0, 0, 0);
        __syncthreads();
    }
#pragma unroll
    for (int m = 0; m < 4; ++m) {
        int row0 = bm + wr * 64 + m * 16 + fq * 4;
#pragma unroll
        for (int n = 0; n < 4; ++n) {
            int col = bn + wc * 64 + n * 16 + fr;
#pragma unroll
            for (int rr = 0; rr < 4; ++rr)
                C[(size_t)(row0 + rr) * N + col] = acc[m][n][rr];
        }
    }
}

// ---------------- launch ----------------

extern "C" void kernel_launch(void* const* d_in, const int* in_sizes, int n_in,
                              void* d_out, int out_size, void* d_ws, size_t ws_size,
                              hipStream_t stream) {
    const float* x1 = (const float*)d_in[0];
    const float* x2 = (const float*)d_in[1];
    const float* mask = (const float*)d_in[2];
    float* out = (float*)d_out;

    char* base = (char*)d_ws;
    const size_t LsLs = (size_t)Ls * Ls;
    const size_t LsCK = (size_t)Ls * CK;
    const long long sPQ = (long long)Ls * KG;

    const bool batched = ws_size >= 132157440ull;

    float* MM2 = (float*)(base);
    float* RN2 = (float*)(base + 18432);
    unsigned short *P, *Q, *ATb2, *RWT2;
    float *G, *S, *T2;
    if (batched) {
        P    = (unsigned short*)(base + 36864);
        Q    = (unsigned short*)(base + 3575808);
        G    = (float*)(base + 7114752);
        S    = (float*)(base + 49582080);
        ATb2 = (unsigned short*)(base + 92049408);
        RWT2 = (unsigned short*)(base + 113283072);
        T2   = G;
    } else {
        P    = (unsigned short*)(base + 36864);
        Q    = (unsigned short*)(base + 1806336);
        G    = (float*)(base + 3575808);
        S    = (float*)(base + 24809472);
        ATb2 = (unsigned short*)(base + 46043136);
        RWT2 = (unsigned short*)(base + 67276800);
        T2   = G;
    }

    mm_k<<<dim3(Ls / 256, 2), 256, 0, stream>>>(mask, MM2);
    gather_rwT_k<<<dim3(Ls / 256, CK, 2), 256, 0, stream>>>(x1, RWT2);

    if (batched) {
        transposePQ_k<<<dim3(2, Ls / 64, 2), 256, 0, stream>>>(x2, P, Q, sPQ, 0);
        mfma_gemm_k<<<dim3(Ls / 128, Ls / 128, 2), 256, 0, stream>>>(
            P, Q, G, Ls, Ls, KG, sPQ, sPQ, (long long)LsLs, 0);
        taps9rn_k<<<dim3(Ls / 256, Ls, 2), 256, 0, stream>>>(G, S, RN2, (long long)LsLs, (long long)LsLs, 0);
        fuse12T_k<<<dim3(Ls / 64, Ls / 64, 2), 256, 0, stream>>>(S, RN2, G, (long long)LsLs, (long long)LsLs, 0);
        softmax_row_k<<<dim3(Ls / 4, 1, 2), 256, 0, stream>>>(G, MM2, ATb2, (long long)LsLs, 0);
    } else {
        for (int z0 = 0; z0 < 2; ++z0) {
            transposePQ_k<<<dim3(2, Ls / 64, 1), 256, 0, stream>>>(x2, P, Q, 0, z0);
            mfma_gemm_k<<<dim3(Ls / 128, Ls / 128, 1), 256, 0, stream>>>(
                P, Q, G, Ls, Ls, KG, 0, 0, 0, 0);
            taps9rn_k<<<dim3(Ls / 256, Ls, 1), 256, 0, stream>>>(G, S, RN2, 0, 0, z0);
            fuse12T_k<<<dim3(Ls / 64, Ls / 64, 1), 256, 0, stream>>>(S, RN2, G, 0, 0, z0);
            softmax_row_k<<<dim3(Ls / 4, 1, 1), 256, 0, stream>>>(G, MM2, ATb2, 0, z0);
        }
    }

    // batched deconv GEMM with 4x3 supertile swizzle: T = A^T @ RW for both samples
    mfma_gemm_k<<<dim3(CK / 128, Ls / 128, 2), 256, 0, stream>>>(
        ATb2, RWT2, T2, Ls, CK, Ls,
        (long long)LsLs, (long long)LsCK, (long long)LsCK, 1);

    scatter2_k<<<dim3(Cc, 1, 2), 256, 0, stream>>>(T2, out);

    (void)in_sizes; (void)n_in; (void)out_size; (void)ws_size;
}

// Round 5
// 271.548 us; speedup vs baseline: 3.7824x; 1.3182x over previous
//
#include <hip/hip_runtime.h>
#include <hip/hip_bf16.h>

// Problem constants (ContextualAttention):
//  B=2, C=128, H=W=96, rate=2 -> h=w=48, L=2304, kernel=4, KSIZE=3, SCALE=10
#define Cc   128
#define Hh   96
#define hs   48
#define Ls   2304      // 48*48
#define CK   2048      // C*16
#define KG   384       // Gram split-K: [h|lo|h] / [h|h|lo]

typedef __attribute__((ext_vector_type(8))) short short8;
typedef __attribute__((ext_vector_type(4))) float f32x4;

__device__ __forceinline__ unsigned short f2bf(float x) {
    unsigned int u = __float_as_uint(x);
    unsigned int r = (u + 0x7fff + ((u >> 16) & 1)) >> 16;   // RNE
    return (unsigned short)r;
}

// unaligned-tolerant 16B vector load (addr is 4B-aligned)
__device__ __forceinline__ f32x4 ld4u(const float* p) {
    f32x4 v; __builtin_memcpy(&v, p, 16); return v;
}

#define GLOAD_LDS16(g, l) \
    __builtin_amdgcn_global_load_lds((__attribute__((address_space(1))) const void*)(g), \
                                     (__attribute__((address_space(3))) void*)(l), 16, 0, 0)

// ---------------- small kernels ----------------

// fused subsample + transpose + bf16 hi/lo split: x2 -> P,Q [l][384]
__global__ __launch_bounds__(256) void transposePQ_k(const float* __restrict__ x2,
                                                     unsigned short* __restrict__ P,
                                                     unsigned short* __restrict__ Q,
                                                     long long sPQ, int z0) {
    const int z = z0 + blockIdx.z;
    const float* x2b = x2 + (size_t)z * Cc * Hh * Hh;
    unsigned short* Pb = P + (size_t)blockIdx.z * sPQ;
    unsigned short* Qb = Q + (size_t)blockIdx.z * sPQ;
    __shared__ float tile[64][65];
    const int c0 = blockIdx.x * 64;      // 0 or 64
    const int l0 = blockIdx.y * 64;      // 36 tiles
    const int t = threadIdx.x;
    const int lt = t & 63, cg = t >> 6;  // cg 0..3
    const int l = l0 + lt;
    const int iy = l / hs, jx = l % hs;
    const int srcoff = iy * (2 * Hh) + 2 * jx;
#pragma unroll
    for (int cc = 0; cc < 16; ++cc) {
        int c = cg * 16 + cc;
        tile[lt][c] = x2b[(size_t)(c0 + c) * (Hh * Hh) + srcoff];
    }
    __syncthreads();
    const int lr = t >> 2, seg = t & 3;
    const int lw = l0 + lr;
    short8 hv0, hv1, lv0, lv1;
#pragma unroll
    for (int k = 0; k < 8; ++k) {
        float x = tile[lr][seg * 16 + k];
        unsigned short h = f2bf(x);
        float hf = __uint_as_float((unsigned)h << 16);
        unsigned short lo = f2bf(x - hf);
        hv0[k] = (short)h; lv0[k] = (short)lo;
    }
#pragma unroll
    for (int k = 0; k < 8; ++k) {
        float x = tile[lr][seg * 16 + 8 + k];
        unsigned short h = f2bf(x);
        float hf = __uint_as_float((unsigned)h << 16);
        unsigned short lo = f2bf(x - hf);
        hv1[k] = (short)h; lv1[k] = (short)lo;
    }
    size_t rowp = (size_t)lw * KG;
    int coff = c0 + seg * 16;
    *(short8*)&Pb[rowp + coff] = hv0;        *(short8*)&Pb[rowp + coff + 8] = hv1;
    *(short8*)&Pb[rowp + 128 + coff] = lv0;  *(short8*)&Pb[rowp + 128 + coff + 8] = lv1;
    *(short8*)&Pb[rowp + 256 + coff] = hv0;  *(short8*)&Pb[rowp + 256 + coff + 8] = hv1;
    *(short8*)&Qb[rowp + coff] = hv0;        *(short8*)&Qb[rowp + coff + 8] = hv1;
    *(short8*)&Qb[rowp + 128 + coff] = hv0;  *(short8*)&Qb[rowp + 128 + coff + 8] = hv1;
    *(short8*)&Qb[rowp + 256 + coff] = lv0;  *(short8*)&Qb[rowp + 256 + coff + 8] = lv1;
}

__global__ __launch_bounds__(256) void mm_k(const float* __restrict__ mask, float* __restrict__ MM) {
    int z = blockIdx.y;
    const float* mb = mask + (size_t)z * hs * hs;
    float* MMb = MM + (size_t)z * Ls;
    int l = blockIdx.x * 256 + threadIdx.x;
    if (l >= Ls) return;
    int ly = l / hs, lx = l % hs;
    float s = 0.f;
    for (int dy = -1; dy <= 1; ++dy)
        for (int dx = -1; dx <= 1; ++dx) {
            int yy = ly + dy, xx = lx + dx;
            if ((unsigned)yy < (unsigned)hs && (unsigned)xx < (unsigned)hs) s += mb[yy * hs + xx];
        }
    float m = s * (1.0f / 9.0f);
    MMb[l] = (m == 0.0f) ? 1.0f : 0.0f;
}

// fused taps + rnorm, vectorized: each thread computes 4 consecutive j for one i.
// G must have >=2KB guard bands on both sides.
__global__ __launch_bounds__(256) void taps9rn_k(const float* __restrict__ G, float* __restrict__ S,
                                                 float* __restrict__ RN, long long zsG, long long zsS, int z0) {
    const float* Gb = G + (size_t)blockIdx.z * zsG;
    float* Sb = S + (size_t)blockIdx.z * zsS;
    float* RNb = RN + (size_t)(z0 + blockIdx.z) * Ls;
    int g = blockIdx.x * 256 + threadIdx.x;      // < 2304*576
    int i = g / 576;
    int jb = (g - i * 576) * 4;
    int iy = i / hs, ix = i % hs;
    int jy = jb / hs, jx0 = jb % hs;
    f32x4 acc = {};
#pragma unroll
    for (int dy = -1; dy <= 1; ++dy) {
        int vy = ((unsigned)(iy + dy) < (unsigned)hs) && ((unsigned)(jy + dy) < (unsigned)hs);
#pragma unroll
        for (int dx = -1; dx <= 1; ++dx) {
            int vi = vy && ((unsigned)(ix + dx) < (unsigned)hs);
            int o = hs * dy + dx;
            int row = vi ? (i + o) : i;
            f32x4 v = ld4u(&Gb[(size_t)row * Ls + jb + o]);
            f32x4 m;
#pragma unroll
            for (int ln = 0; ln < 4; ++ln)
                m[ln] = (vi && ((unsigned)(jx0 + ln + dx) < (unsigned)hs)) ? 1.f : 0.f;
            acc += v * m;
        }
    }
    __builtin_memcpy(&Sb[(size_t)i * Ls + jb], &acc, 16);
    int dd = i - jb;
    if ((unsigned)dd < 4u) RNb[i] = 1.0f / fmaxf(sqrtf(acc[dd]), 1e-4f);
}

// fused fuse2(fuse1) with transposed output, vectorized 4j x 4i per thread.
// S must have >=2KB guard bands on both sides.
__global__ __launch_bounds__(256) void fuse12T_k(const float* __restrict__ S, const float* __restrict__ RN,
                                                 float* __restrict__ ZT, long long zsS, long long zsZT, int z0) {
    const float* Sb = S + (size_t)blockIdx.z * zsS;
    float* ZTb = ZT + (size_t)blockIdx.z * zsZT;
    const float* RNb = RN + (size_t)(z0 + blockIdx.z) * Ls;
    __shared__ float tile[64][65];
    const int i0 = blockIdx.y * 64, j0 = blockIdx.x * 64;
    const int t = threadIdx.x;
    const int jg = t & 15, tit = t >> 4;
    const int jb = j0 + jg * 4;
    const int jy0 = jb / hs, jx0 = jb % hs;

    // per-tap j-side bases and masks (cc is consecutive across the 4 lanes)
    int ccb[9]; f32x4 m4[9];
#pragma unroll
    for (int d2 = -1; d2 <= 1; ++d2) {
        int cl[4], vb[4];
#pragma unroll
        for (int ln = 0; ln < 4; ++ln) {
            int j2 = (jx0 + ln) * hs + jy0 + d2;
            int vv = ((unsigned)j2 < (unsigned)Ls) ? 1 : 0;
            int c = vv ? ((j2 % hs) * hs + j2 / hs) : 0;
            cl[ln] = c; vb[ln] = vv;
        }
        int base = 0;
#pragma unroll
        for (int ln = 0; ln < 4; ++ln) if (vb[ln]) base = cl[ln] - ln;
#pragma unroll
        for (int d1 = -1; d1 <= 1; ++d1) {
            int idx = (d2 + 1) * 3 + (d1 + 1);
            ccb[idx] = base + d1;
            f32x4 mm;
#pragma unroll
            for (int ln = 0; ln < 4; ++ln) {
                int cc = cl[ln] + d1;
                mm[ln] = (vb[ln] && ((unsigned)cc < (unsigned)Ls)) ? 1.f : 0.f;
            }
            m4[idx] = mm;
        }
    }

    f32x4 acc[4] = {};
#pragma unroll
    for (int kk = 0; kk < 4; ++kk) {
        const int i = i0 + tit * 4 + kk;
        const int iy = i / hs, ix = i % hs;
        const int tif = ix * hs + iy;
#pragma unroll
        for (int d2 = -1; d2 <= 1; ++d2) {
            int i2 = tif + d2;
            int vi = ((unsigned)i2 < (unsigned)Ls) ? 1 : 0;
            int r = vi ? ((i2 % hs) * hs + i2 / hs) : 1;
#pragma unroll
            for (int d1 = -1; d1 <= 1; ++d1) {
                int rr = r + d1;
                int vr = vi && ((unsigned)rr < (unsigned)Ls);
                int rrc = vr ? rr : 0;
                float w = RNb[rrc];
                w = vr ? w : 0.f;
                int idx = (d2 + 1) * 3 + (d1 + 1);
                f32x4 v = ld4u(&Sb[(size_t)rrc * Ls + ccb[idx]]);
                acc[kk] += v * m4[idx] * w;
            }
        }
    }
#pragma unroll
    for (int kk = 0; kk < 4; ++kk) {
        int ti = tit * 4 + kk;
        tile[ti][jg * 4 + 0] = acc[kk][0];
        tile[ti][jg * 4 + 1] = acc[kk][1];
        tile[ti][jg * 4 + 2] = acc[kk][2];
        tile[ti][jg * 4 + 3] = acc[kk][3];
    }
    __syncthreads();
    const int r2 = t >> 2, cs = (t & 3) * 16;
    float vbuf[16];
#pragma unroll
    for (int k = 0; k < 16; ++k) vbuf[k] = tile[cs + k][r2];
    float* dst = &ZTb[(size_t)(j0 + r2) * Ls + i0 + cs];
#pragma unroll
    for (int k = 0; k < 4; ++k)
        *(float4*)&dst[k * 4] = *(float4*)&vbuf[k * 4];
}

// row softmax over ZT[p][l] (coalesced), writes bf16 AT[p][l]
__global__ __launch_bounds__(256) void softmax_row_k(const float* __restrict__ ZT, const float* __restrict__ MM,
                                                     unsigned short* __restrict__ AT, long long zsZT, int z0) {
    const int z = z0 + blockIdx.z;
    const float* ZTb = ZT + (size_t)blockIdx.z * zsZT;
    const float* MMb = MM + (size_t)z * Ls;
    unsigned short* ATb = AT + (size_t)z * Ls * Ls;
    const int w = threadIdx.x >> 6, lane = threadIdx.x & 63;
    const int p = blockIdx.x * 4 + w;
    const float* row = ZTb + (size_t)p * Ls;
    float v[36];
    float mx = -3.4e38f;
#pragma unroll
    for (int k = 0; k < 9; ++k) {
        const float4 zv = *(const float4*)&row[k * 256 + lane * 4];
        const float4 m = *(const float4*)&MMb[k * 256 + lane * 4];
        v[4 * k + 0] = zv.x * m.x * 10.f;
        v[4 * k + 1] = zv.y * m.y * 10.f;
        v[4 * k + 2] = zv.z * m.z * 10.f;
        v[4 * k + 3] = zv.w * m.w * 10.f;
        mx = fmaxf(mx, fmaxf(fmaxf(v[4 * k], v[4 * k + 1]), fmaxf(v[4 * k + 2], v[4 * k + 3])));
    }
#pragma unroll
    for (int off = 32; off; off >>= 1) mx = fmaxf(mx, __shfl_xor(mx, off));
    float sum = 0.f;
#pragma unroll
    for (int kk = 0; kk < 36; ++kk) { v[kk] = expf(v[kk] - mx); sum += v[kk]; }
#pragma unroll
    for (int off = 32; off; off >>= 1) sum += __shfl_xor(sum, off);
    const float rs = 1.0f / sum;
#pragma unroll
    for (int k = 0; k < 9; ++k) {
        const float4 m = *(const float4*)&MMb[k * 256 + lane * 4];
        ushort4 o;
        o.x = f2bf(fmaxf(v[4 * k + 0] * rs * m.x, 1e-8f));
        o.y = f2bf(fmaxf(v[4 * k + 1] * rs * m.y, 1e-8f));
        o.z = f2bf(fmaxf(v[4 * k + 2] * rs * m.z, 1e-8f));
        o.w = f2bf(fmaxf(v[4 * k + 3] * rs * m.w, 1e-8f));
        *(ushort4*)&ATb[(size_t)p * Ls + k * 256 + lane * 4] = o;
    }
}

// raw_w^T gather (bf16, N-major K-contiguous), z-batched
__global__ __launch_bounds__(256) void gather_rwT_k(const float* __restrict__ x1, unsigned short* __restrict__ RWT) {
    const int z = blockIdx.z;
    const float* x1b = x1 + (size_t)z * Cc * Hh * Hh;
    unsigned short* R = RWT + (size_t)z * CK * Ls;
    int l = blockIdx.x * 256 + threadIdx.x;   // < 2304
    int ck = blockIdx.y;                      // < 2048
    int c = ck >> 4, a = (ck >> 2) & 3, b2 = ck & 3;
    int ly = l / hs, lx = l % hs;
    int u = 2 * ly + a - 1, vv = 2 * lx + b2 - 1;
    float val = ((unsigned)u < (unsigned)Hh && (unsigned)vv < (unsigned)Hh) ? x1b[c * (Hh * Hh) + u * Hh + vv] : 0.0f;
    R[(size_t)ck * Ls + l] = f2bf(val);
}

// per-channel LDS-accumulated scatter: block = (channel, z)
__global__ __launch_bounds__(256) void scatter2_k(const float* __restrict__ T, float* __restrict__ out) {
    const int z = blockIdx.z;
    const int c = blockIdx.x;
    const float* Tb = T + (size_t)z * Ls * CK;
    float* outb = out + (size_t)z * Cc * Hh * Hh + (size_t)c * Hh * Hh;
    __shared__ float o[Hh * Hh];
    const int t = threadIdx.x;
    for (int i = t; i < Hh * Hh; i += 256) o[i] = 0.f;
    __syncthreads();
#pragma unroll
    for (int rep = 0; rep < 9; ++rep) {
        int p = rep * 256 + t;                 // 0..2303
        int i = p / hs, jj = p % hs;
        const float4* tp = (const float4*)&Tb[(size_t)p * CK + c * 16];
        float4 va = tp[0], vb = tp[1], vc = tp[2], vd = tp[3];
        float vals[16] = {va.x, va.y, va.z, va.w, vb.x, vb.y, vb.z, vb.w,
                          vc.x, vc.y, vc.z, vc.w, vd.x, vd.y, vd.z, vd.w};
#pragma unroll
        for (int a = 0; a < 4; ++a) {
            int Y = 2 * i + a - 1;
            if ((unsigned)Y >= (unsigned)Hh) continue;
#pragma unroll
            for (int b2 = 0; b2 < 4; ++b2) {
                int X = 2 * jj + b2 - 1;
                if ((unsigned)X >= (unsigned)Hh) continue;
                atomicAdd(&o[Y * Hh + X], vals[a * 4 + b2]);
            }
        }
    }
    __syncthreads();
    for (int i = t; i < Hh * Hh; i += 256) outb[i] = 0.25f * o[i];
}

// ---------------- bf16 MFMA GEMM: C[M,N] = A[M,K] * Bt[N,K]^T, z-batched ----------------
__global__ __launch_bounds__(256) void mfma_gemm_k(const unsigned short* __restrict__ A,
                                                   const unsigned short* __restrict__ Bt,
                                                   float* __restrict__ C, int M, int N, int K,
                                                   long long sA, long long sB, long long sC,
                                                   int supertile) {
    A  += (size_t)blockIdx.z * sA;
    Bt += (size_t)blockIdx.z * sB;
    C  += (size_t)blockIdx.z * sC;

    const int nb = gridDim.x * gridDim.y;
    const int flat = blockIdx.y * gridDim.x + blockIdx.x;
    const int q = nb >> 3, r = nb & 7;
    const int xcd = flat & 7, sidx = flat >> 3;
    const int wg = (xcd < r ? xcd * (q + 1) : r * (q + 1) + (xcd - r) * q) + sidx;
    int bm, bn;
    if (supertile) {
        int st = wg / 12, tt = wg % 12;
        int stn = st & 3, stm = st >> 2;
        int tn = tt & 3, tm = tt >> 2;
        bn = (stn * 4 + tn) * 128;
        bm = (stm * 3 + tm) * 128;
    } else {
        bm = (wg / gridDim.x) * 128;
        bn = (wg % gridDim.x) * 128;
    }

    __shared__ __align__(16) unsigned short Asm[128 * 32];
    __shared__ __align__(16) unsigned short Bsm[128 * 32];
    const int t = threadIdx.x;
    const int lane = t & 63, w = t >> 6;
    const int wr = w >> 1, wc = w & 1;

    const int rA = 32 * w + (lane >> 2);
    const int kA = (lane & 3) * 8;
    const unsigned short* gA0 = A + (size_t)(bm + rA) * K + kA;
    const unsigned short* gA1 = gA0 + (size_t)16 * K;
    const unsigned short* gB0 = Bt + (size_t)(bn + rA) * K + kA;
    const unsigned short* gB1 = gB0 + (size_t)16 * K;
    unsigned short* lA0 = &Asm[(2 * w) * 512];
    unsigned short* lA1 = &Asm[(2 * w + 1) * 512];
    unsigned short* lB0 = &Bsm[(2 * w) * 512];
    unsigned short* lB1 = &Bsm[(2 * w + 1) * 512];

    const int fr = lane & 15, fq = lane >> 4;
    f32x4 acc[4][4] = {};

    for (int k0 = 0; k0 < K; k0 += 32) {
        GLOAD_LDS16(gA0 + k0, lA0);
        GLOAD_LDS16(gA1 + k0, lA1);
        GLOAD_LDS16(gB0 + k0, lB0);
        GLOAD_LDS16(gB1 + k0, lB1);
        __syncthreads();
        short8 av[4], bv[4];
#pragma unroll
        for (int m = 0; m < 4; ++m)
            av[m] = *(const short8*)&Asm[(wr * 64 + m * 16 + fr) * 32 + fq * 8];
#pragma unroll
        for (int n = 0; n < 4; ++n)
            bv[n] = *(const short8*)&Bsm[(wc * 64 + n * 16 + fr) * 32 + fq * 8];
#pragma unroll
        for (int m = 0; m < 4; ++m)
#pragma unroll
            for (int n = 0; n < 4; ++n)
                acc[m][n] = __builtin_amdgcn_mfma_f32_16x16x32_bf16(av[m], bv[n], acc[m][n], 0, 0, 0);
        __syncthreads();
    }
#pragma unroll
    for (int m = 0; m < 4; ++m) {
        int row0 = bm + wr * 64 + m * 16 + fq * 4;
#pragma unroll
        for (int n = 0; n < 4; ++n) {
            int col = bn + wc * 64 + n * 16 + fr;
#pragma unroll
            for (int rr = 0; rr < 4; ++rr)
                C[(size_t)(row0 + rr) * N + col] = acc[m][n][rr];
        }
    }
}

// ---------------- launch ----------------

extern "C" void kernel_launch(void* const* d_in, const int* in_sizes, int n_in,
                              void* d_out, int out_size, void* d_ws, size_t ws_size,
                              hipStream_t stream) {
    const float* x1 = (const float*)d_in[0];
    const float* x2 = (const float*)d_in[1];
    const float* mask = (const float*)d_in[2];
    float* out = (float*)d_out;

    char* base = (char*)d_ws;
    const size_t LsLs = (size_t)Ls * Ls;
    const size_t LsCK = (size_t)Ls * CK;
    const long long sPQ = (long long)Ls * KG;

    const bool batched = ws_size >= 132175872ull;

    float* MM2 = (float*)(base);
    float* RN2 = (float*)(base + 20480);
    unsigned short *P, *Q, *ATb2, *RWT2;
    float *G, *S, *T2;
    if (batched) {
        P    = (unsigned short*)(base + 40960);
        Q    = (unsigned short*)(base + 3584000);
        G    = (float*)(base + 7127040);        // 2KB guards at 7124992 / 49594368
        S    = (float*)(base + 49598464);       // 2KB guards at 49596416 / 92065792
        ATb2 = (unsigned short*)(base + 92067840);
        RWT2 = (unsigned short*)(base + 113301504);   // end 132,175,872
        T2   = (float*)base;                    // overlay [0, 37.7MB): dead by deconv time
    } else {
        P    = (unsigned short*)(base + 40960);
        Q    = (unsigned short*)(base + 1812480);
        G    = (float*)(base + 3586048);        // guards around
        S    = (float*)(base + 24823808);
        ATb2 = (unsigned short*)(base + 46059520);
        RWT2 = (unsigned short*)(base + 67293184);    // end 86,167,552
        T2   = (float*)base;
    }

    mm_k<<<dim3(Ls / 256, 2), 256, 0, stream>>>(mask, MM2);
    gather_rwT_k<<<dim3(Ls / 256, CK, 2), 256, 0, stream>>>(x1, RWT2);

    const int tapsGrid = (Ls * 576) / 256;   // 5184

    if (batched) {
        transposePQ_k<<<dim3(2, Ls / 64, 2), 256, 0, stream>>>(x2, P, Q, sPQ, 0);
        mfma_gemm_k<<<dim3(Ls / 128, Ls / 128, 2), 256, 0, stream>>>(
            P, Q, G, Ls, Ls, KG, sPQ, sPQ, (long long)LsLs, 0);
        taps9rn_k<<<dim3(tapsGrid, 1, 2), 256, 0, stream>>>(G, S, RN2, (long long)LsLs, (long long)LsLs, 0);
        fuse12T_k<<<dim3(Ls / 64, Ls / 64, 2), 256, 0, stream>>>(S, RN2, G, (long long)LsLs, (long long)LsLs, 0);
        softmax_row_k<<<dim3(Ls / 4, 1, 2), 256, 0, stream>>>(G, MM2, ATb2, (long long)LsLs, 0);
    } else {
        for (int z0 = 0; z0 < 2; ++z0) {
            transposePQ_k<<<dim3(2, Ls / 64, 1), 256, 0, stream>>>(x2, P, Q, 0, z0);
            mfma_gemm_k<<<dim3(Ls / 128, Ls / 128, 1), 256, 0, stream>>>(
                P, Q, G, Ls, Ls, KG, 0, 0, 0, 0);
            taps9rn_k<<<dim3(tapsGrid, 1, 1), 256, 0, stream>>>(G, S, RN2, 0, 0, z0);
            fuse12T_k<<<dim3(Ls / 64, Ls / 64, 1), 256, 0, stream>>>(S, RN2, G, 0, 0, z0);
            softmax_row_k<<<dim3(Ls / 4, 1, 1), 256, 0, stream>>>(G, MM2, ATb2, 0, z0);
        }
    }

    // batched deconv GEMM with 4x3 supertile swizzle: T = A^T @ RW for both samples
    mfma_gemm_k<<<dim3(CK / 128, Ls / 128, 2), 256, 0, stream>>>(
        ATb2, RWT2, T2, Ls, CK, Ls,
        (long long)LsLs, (long long)LsCK, (long long)LsCK, 1);

    scatter2_k<<<dim3(Cc, 1, 2), 256, 0, stream>>>(T2, out);

    (void)in_sizes; (void)n_in; (void)out_size; (void)ws_size;
}

// Round 6
// 223.770 us; speedup vs baseline: 4.5900x; 1.2135x over previous
//
#include <hip/hip_runtime.h>
#include <hip/hip_bf16.h>

// Problem constants (ContextualAttention):
//  B=2, C=128, H=W=96, rate=2 -> h=w=48, L=2304, kernel=4, KSIZE=3, SCALE=10
#define Cc   128
#define Hh   96
#define hs   48
#define Ls   2304      // 48*48
#define CK   2048      // C*16
#define KG   384       // Gram split-K: [h|lo|h] / [h|h|lo]

typedef __attribute__((ext_vector_type(8))) short short8;
typedef __attribute__((ext_vector_type(4))) float f32x4;

__device__ __forceinline__ unsigned short f2bf(float x) {
    unsigned int u = __float_as_uint(x);
    unsigned int r = (u + 0x7fff + ((u >> 16) & 1)) >> 16;   // RNE
    return (unsigned short)r;
}
__device__ __forceinline__ float bf2f(unsigned short h) {
    return __uint_as_float((unsigned)h << 16);
}

// unaligned-tolerant 16B vector load (addr is 4B-aligned)
__device__ __forceinline__ f32x4 ld4u(const float* p) {
    f32x4 v; __builtin_memcpy(&v, p, 16); return v;
}

#define GLOAD_LDS16(g, l) \
    __builtin_amdgcn_global_load_lds((__attribute__((address_space(1))) const void*)(g), \
                                     (__attribute__((address_space(3))) void*)(l), 16, 0, 0)

// ---------------- small kernels ----------------

// fused subsample + transpose + bf16 hi/lo split: x2 -> P,Q [l][384]
__global__ __launch_bounds__(256) void transposePQ_k(const float* __restrict__ x2,
                                                     unsigned short* __restrict__ P,
                                                     unsigned short* __restrict__ Q,
                                                     long long sPQ, int z0) {
    const int z = z0 + blockIdx.z;
    const float* x2b = x2 + (size_t)z * Cc * Hh * Hh;
    unsigned short* Pb = P + (size_t)blockIdx.z * sPQ;
    unsigned short* Qb = Q + (size_t)blockIdx.z * sPQ;
    __shared__ float tile[64][65];
    const int c0 = blockIdx.x * 64;      // 0 or 64
    const int l0 = blockIdx.y * 64;      // 36 tiles
    const int t = threadIdx.x;
    const int lt = t & 63, cg = t >> 6;  // cg 0..3
    const int l = l0 + lt;
    const int iy = l / hs, jx = l % hs;
    const int srcoff = iy * (2 * Hh) + 2 * jx;
#pragma unroll
    for (int cc = 0; cc < 16; ++cc) {
        int c = cg * 16 + cc;
        tile[lt][c] = x2b[(size_t)(c0 + c) * (Hh * Hh) + srcoff];
    }
    __syncthreads();
    const int lr = t >> 2, seg = t & 3;
    const int lw = l0 + lr;
    short8 hv0, hv1, lv0, lv1;
#pragma unroll
    for (int k = 0; k < 8; ++k) {
        float x = tile[lr][seg * 16 + k];
        unsigned short h = f2bf(x);
        float hf = __uint_as_float((unsigned)h << 16);
        unsigned short lo = f2bf(x - hf);
        hv0[k] = (short)h; lv0[k] = (short)lo;
    }
#pragma unroll
    for (int k = 0; k < 8; ++k) {
        float x = tile[lr][seg * 16 + 8 + k];
        unsigned short h = f2bf(x);
        float hf = __uint_as_float((unsigned)h << 16);
        unsigned short lo = f2bf(x - hf);
        hv1[k] = (short)h; lv1[k] = (short)lo;
    }
    size_t rowp = (size_t)lw * KG;
    int coff = c0 + seg * 16;
    *(short8*)&Pb[rowp + coff] = hv0;        *(short8*)&Pb[rowp + coff + 8] = hv1;
    *(short8*)&Pb[rowp + 128 + coff] = lv0;  *(short8*)&Pb[rowp + 128 + coff + 8] = lv1;
    *(short8*)&Pb[rowp + 256 + coff] = hv0;  *(short8*)&Pb[rowp + 256 + coff + 8] = hv1;
    *(short8*)&Qb[rowp + coff] = hv0;        *(short8*)&Qb[rowp + coff + 8] = hv1;
    *(short8*)&Qb[rowp + 128 + coff] = hv0;  *(short8*)&Qb[rowp + 128 + coff + 8] = hv1;
    *(short8*)&Qb[rowp + 256 + coff] = lv0;  *(short8*)&Qb[rowp + 256 + coff + 8] = lv1;
}

__global__ __launch_bounds__(256) void mm_k(const float* __restrict__ mask, float* __restrict__ MM) {
    int z = blockIdx.y;
    const float* mb = mask + (size_t)z * hs * hs;
    float* MMb = MM + (size_t)z * Ls;
    int l = blockIdx.x * 256 + threadIdx.x;
    if (l >= Ls) return;
    int ly = l / hs, lx = l % hs;
    float s = 0.f;
    for (int dy = -1; dy <= 1; ++dy)
        for (int dx = -1; dx <= 1; ++dx) {
            int yy = ly + dy, xx = lx + dx;
            if ((unsigned)yy < (unsigned)hs && (unsigned)xx < (unsigned)hs) s += mb[yy * hs + xx];
        }
    float m = s * (1.0f / 9.0f);
    MMb[l] = (m == 0.0f) ? 1.0f : 0.0f;
}

// fused taps + rnorm, vectorized: each thread computes 4 consecutive j for one i.
// G must have >=2KB guard bands on both sides.
__global__ __launch_bounds__(256) void taps9rn_k(const float* __restrict__ G, float* __restrict__ S,
                                                 float* __restrict__ RN, long long zsG, long long zsS, int z0) {
    const float* Gb = G + (size_t)blockIdx.z * zsG;
    float* Sb = S + (size_t)blockIdx.z * zsS;
    float* RNb = RN + (size_t)(z0 + blockIdx.z) * Ls;
    int g = blockIdx.x * 256 + threadIdx.x;      // < 2304*576
    int i = g / 576;
    int jb = (g - i * 576) * 4;
    int iy = i / hs, ix = i % hs;
    int jy = jb / hs, jx0 = jb % hs;
    f32x4 acc = {};
#pragma unroll
    for (int dy = -1; dy <= 1; ++dy) {
        int vy = ((unsigned)(iy + dy) < (unsigned)hs) && ((unsigned)(jy + dy) < (unsigned)hs);
#pragma unroll
        for (int dx = -1; dx <= 1; ++dx) {
            int vi = vy && ((unsigned)(ix + dx) < (unsigned)hs);
            int o = hs * dy + dx;
            int row = vi ? (i + o) : i;
            f32x4 v = ld4u(&Gb[(size_t)row * Ls + jb + o]);
            f32x4 m;
#pragma unroll
            for (int ln = 0; ln < 4; ++ln)
                m[ln] = (vi && ((unsigned)(jx0 + ln + dx) < (unsigned)hs)) ? 1.f : 0.f;
            acc += v * m;
        }
    }
    __builtin_memcpy(&Sb[(size_t)i * Ls + jb], &acc, 16);
    int dd = i - jb;
    if ((unsigned)dd < 4u) RNb[i] = 1.0f / fmaxf(sqrtf(acc[dd]), 1e-4f);
}

// fused fuse2(fuse1) with transposed output, vectorized 4j x 4i per thread.
// S must have >=2KB guard bands on both sides.
__global__ __launch_bounds__(256) void fuse12T_k(const float* __restrict__ S, const float* __restrict__ RN,
                                                 float* __restrict__ ZT, long long zsS, long long zsZT, int z0) {
    const float* Sb = S + (size_t)blockIdx.z * zsS;
    float* ZTb = ZT + (size_t)blockIdx.z * zsZT;
    const float* RNb = RN + (size_t)(z0 + blockIdx.z) * Ls;
    __shared__ float tile[64][65];
    const int i0 = blockIdx.y * 64, j0 = blockIdx.x * 64;
    const int t = threadIdx.x;
    const int jg = t & 15, tit = t >> 4;
    const int jb = j0 + jg * 4;
    const int jy0 = jb / hs, jx0 = jb % hs;

    int ccb[9]; f32x4 m4[9];
#pragma unroll
    for (int d2 = -1; d2 <= 1; ++d2) {
        int cl[4], vb[4];
#pragma unroll
        for (int ln = 0; ln < 4; ++ln) {
            int j2 = (jx0 + ln) * hs + jy0 + d2;
            int vv = ((unsigned)j2 < (unsigned)Ls) ? 1 : 0;
            int c = vv ? ((j2 % hs) * hs + j2 / hs) : 0;
            cl[ln] = c; vb[ln] = vv;
        }
        int base = 0;
#pragma unroll
        for (int ln = 0; ln < 4; ++ln) if (vb[ln]) base = cl[ln] - ln;
#pragma unroll
        for (int d1 = -1; d1 <= 1; ++d1) {
            int idx = (d2 + 1) * 3 + (d1 + 1);
            ccb[idx] = base + d1;
            f32x4 mm;
#pragma unroll
            for (int ln = 0; ln < 4; ++ln) {
                int cc = cl[ln] + d1;
                mm[ln] = (vb[ln] && ((unsigned)cc < (unsigned)Ls)) ? 1.f : 0.f;
            }
            m4[idx] = mm;
        }
    }

    f32x4 acc[4] = {};
#pragma unroll
    for (int kk = 0; kk < 4; ++kk) {
        const int i = i0 + tit * 4 + kk;
        const int iy = i / hs, ix = i % hs;
        const int tif = ix * hs + iy;
#pragma unroll
        for (int d2 = -1; d2 <= 1; ++d2) {
            int i2 = tif + d2;
            int vi = ((unsigned)i2 < (unsigned)Ls) ? 1 : 0;
            int r = vi ? ((i2 % hs) * hs + i2 / hs) : 1;
#pragma unroll
            for (int d1 = -1; d1 <= 1; ++d1) {
                int rr = r + d1;
                int vr = vi && ((unsigned)rr < (unsigned)Ls);
                int rrc = vr ? rr : 0;
                float w = RNb[rrc];
                w = vr ? w : 0.f;
                int idx = (d2 + 1) * 3 + (d1 + 1);
                f32x4 v = ld4u(&Sb[(size_t)rrc * Ls + ccb[idx]]);
                acc[kk] += v * m4[idx] * w;
            }
        }
    }
#pragma unroll
    for (int kk = 0; kk < 4; ++kk) {
        int ti = tit * 4 + kk;
        tile[ti][jg * 4 + 0] = acc[kk][0];
        tile[ti][jg * 4 + 1] = acc[kk][1];
        tile[ti][jg * 4 + 2] = acc[kk][2];
        tile[ti][jg * 4 + 3] = acc[kk][3];
    }
    __syncthreads();
    const int r2 = t >> 2, cs = (t & 3) * 16;
    float vbuf[16];
#pragma unroll
    for (int k = 0; k < 16; ++k) vbuf[k] = tile[cs + k][r2];
    float* dst = &ZTb[(size_t)(j0 + r2) * Ls + i0 + cs];
#pragma unroll
    for (int k = 0; k < 4; ++k)
        *(float4*)&dst[k * 4] = *(float4*)&vbuf[k * 4];
}

// row softmax over ZT[p][l] (coalesced), writes bf16 AT[p][l]
__global__ __launch_bounds__(256) void softmax_row_k(const float* __restrict__ ZT, const float* __restrict__ MM,
                                                     unsigned short* __restrict__ AT, long long zsZT, int z0) {
    const int z = z0 + blockIdx.z;
    const float* ZTb = ZT + (size_t)blockIdx.z * zsZT;
    const float* MMb = MM + (size_t)z * Ls;
    unsigned short* ATb = AT + (size_t)z * Ls * Ls;
    const int w = threadIdx.x >> 6, lane = threadIdx.x & 63;
    const int p = blockIdx.x * 4 + w;
    const float* row = ZTb + (size_t)p * Ls;
    float v[36];
    float mx = -3.4e38f;
#pragma unroll
    for (int k = 0; k < 9; ++k) {
        const float4 zv = *(const float4*)&row[k * 256 + lane * 4];
        const float4 m = *(const float4*)&MMb[k * 256 + lane * 4];
        v[4 * k + 0] = zv.x * m.x * 10.f;
        v[4 * k + 1] = zv.y * m.y * 10.f;
        v[4 * k + 2] = zv.z * m.z * 10.f;
        v[4 * k + 3] = zv.w * m.w * 10.f;
        mx = fmaxf(mx, fmaxf(fmaxf(v[4 * k], v[4 * k + 1]), fmaxf(v[4 * k + 2], v[4 * k + 3])));
    }
#pragma unroll
    for (int off = 32; off; off >>= 1) mx = fmaxf(mx, __shfl_xor(mx, off));
    float sum = 0.f;
#pragma unroll
    for (int kk = 0; kk < 36; ++kk) { v[kk] = expf(v[kk] - mx); sum += v[kk]; }
#pragma unroll
    for (int off = 32; off; off >>= 1) sum += __shfl_xor(sum, off);
    const float rs = 1.0f / sum;
#pragma unroll
    for (int k = 0; k < 9; ++k) {
        const float4 m = *(const float4*)&MMb[k * 256 + lane * 4];
        ushort4 o;
        o.x = f2bf(fmaxf(v[4 * k + 0] * rs * m.x, 1e-8f));
        o.y = f2bf(fmaxf(v[4 * k + 1] * rs * m.y, 1e-8f));
        o.z = f2bf(fmaxf(v[4 * k + 2] * rs * m.z, 1e-8f));
        o.w = f2bf(fmaxf(v[4 * k + 3] * rs * m.w, 1e-8f));
        *(ushort4*)&ATb[(size_t)p * Ls + k * 256 + lane * 4] = o;
    }
}

// raw_w^T gather (bf16, N-major K-contiguous), z-batched
__global__ __launch_bounds__(256) void gather_rwT_k(const float* __restrict__ x1, unsigned short* __restrict__ RWT) {
    const int z = blockIdx.z;
    const float* x1b = x1 + (size_t)z * Cc * Hh * Hh;
    unsigned short* R = RWT + (size_t)z * CK * Ls;
    int l = blockIdx.x * 256 + threadIdx.x;   // < 2304
    int ck = blockIdx.y;                      // < 2048
    int c = ck >> 4, a = (ck >> 2) & 3, b2 = ck & 3;
    int ly = l / hs, lx = l % hs;
    int u = 2 * ly + a - 1, vv = 2 * lx + b2 - 1;
    float val = ((unsigned)u < (unsigned)Hh && (unsigned)vv < (unsigned)Hh) ? x1b[c * (Hh * Hh) + u * Hh + vv] : 0.0f;
    R[(size_t)ck * Ls + l] = f2bf(val);
}

// LDS-gather scatter: block = (channel, yhalf, z); T is bf16.
// out[c,Y,X] = 0.25 * sum over <=4 covering (i,j,a,b): T[(i*48+j)*2048 + c*16 + a*4 + b]
__global__ __launch_bounds__(256) void scatter3_k(const unsigned short* __restrict__ T, float* __restrict__ out) {
    const int z = blockIdx.z;
    const int c = blockIdx.x;
    const int yh = blockIdx.y;                 // 0 or 1
    const unsigned short* Tb = T + (size_t)z * Ls * CK + (size_t)c * 16;
    float* outb = out + (size_t)z * Cc * Hh * Hh + (size_t)c * Hh * Hh;
    const int i0 = (yh == 0) ? 0 : 23;          // i range [i0, i0+25)
    __shared__ unsigned short Tl[1200 * 16];    // 25*48 rows x 16 bf16 = 38.4 KB
    const int t = threadIdx.x;
#pragma unroll
    for (int rep = 0; rep < 5; ++rep) {
        int p = rep * 256 + t;
        if (p < 1200)
            __builtin_memcpy(&Tl[p * 16], &Tb[(size_t)(i0 * hs + p) * CK], 32);
    }
    __syncthreads();
#pragma unroll
    for (int rep = 0; rep < 5; ++rep) {
        int idx4 = rep * 256 + t;              // < 1152 (48 rows x 24 float4)
        if (idx4 >= 1152) break;
        int Y = yh * 48 + idx4 / 24;
        int X0 = (idx4 % 24) * 4;
        float o4[4];
#pragma unroll
        for (int xi = 0; xi < 4; ++xi) {
            int X = X0 + xi;
            int a0 = (Y + 1) & 1, b0 = (X + 1) & 1;
            float s = 0.f;
#pragma unroll
            for (int ai = 0; ai < 2; ++ai) {
                int a = a0 + 2 * ai;
                int i = (Y + 1 - a) >> 1;
                if ((unsigned)i >= (unsigned)hs) continue;
#pragma unroll
                for (int bi = 0; bi < 2; ++bi) {
                    int b2 = b0 + 2 * bi;
                    int jj = (X + 1 - b2) >> 1;
                    if ((unsigned)jj >= (unsigned)hs) continue;
                    s += bf2f(Tl[((i - i0) * hs + jj) * 16 + a * 4 + b2]);
                }
            }
            o4[xi] = 0.25f * s;
        }
        *(float4*)&outb[Y * Hh + X0] = *(float4*)&o4[0];
    }
}

// ---------------- bf16 MFMA GEMM, 2-phase double-buffered ----------------
// C[M,N] = A[M,K] * Bt[N,K]^T, z-batched. SUPER: 4x3 supertile remap (grid must be 16x18).
// CBF16: C written as bf16, else f32.
template <int SUPER, int CBF16>
__global__ __launch_bounds__(256) void mfma_gemm_k(const unsigned short* __restrict__ A,
                                                   const unsigned short* __restrict__ Bt,
                                                   void* __restrict__ Cv, int M, int N, int K,
                                                   long long sA, long long sB, long long sC) {
    A  += (size_t)blockIdx.z * sA;
    Bt += (size_t)blockIdx.z * sB;
    float* Cf = (float*)Cv + (CBF16 ? 0 : (size_t)blockIdx.z * sC);
    unsigned short* Ch = (unsigned short*)Cv + (CBF16 ? (size_t)blockIdx.z * sC : 0);

    // bijective XCD-aware remap over (x,y)
    const int nb = gridDim.x * gridDim.y;
    const int flat = blockIdx.y * gridDim.x + blockIdx.x;
    const int q = nb >> 3, r = nb & 7;
    const int xcd = flat & 7, sidx = flat >> 3;
    const int wg = (xcd < r ? xcd * (q + 1) : r * (q + 1) + (xcd - r) * q) + sidx;
    int bm, bn;
    if (SUPER) {
        int st = wg / 12, tt = wg % 12;
        int stn = st & 3, stm = st >> 2;     // 4 x 6 supertile grid
        int tn = tt & 3, tm = tt >> 2;       // 4(n) x 3(m) within
        bn = (stn * 4 + tn) * 128;
        bm = (stm * 3 + tm) * 128;
    } else {
        bm = (wg / gridDim.x) * 128;
        bn = (wg % gridDim.x) * 128;
    }

    __shared__ __align__(16) unsigned short Asm[2][128 * 32];
    __shared__ __align__(16) unsigned short Bsm[2][128 * 32];
    const int t = threadIdx.x;
    const int lane = t & 63, w = t >> 6;
    const int wr = w >> 1, wc = w & 1;

    const int rA = 32 * w + (lane >> 2);
    const int kA = (lane & 3) * 8;
    const unsigned short* gA0 = A + (size_t)(bm + rA) * K + kA;
    const unsigned short* gA1 = gA0 + (size_t)16 * K;
    const unsigned short* gB0 = Bt + (size_t)(bn + rA) * K + kA;
    const unsigned short* gB1 = gB0 + (size_t)16 * K;

#define STAGE4(b, koff) do { \
        GLOAD_LDS16(gA0 + (koff), &Asm[b][(2 * w) * 512]); \
        GLOAD_LDS16(gA1 + (koff), &Asm[b][(2 * w + 1) * 512]); \
        GLOAD_LDS16(gB0 + (koff), &Bsm[b][(2 * w) * 512]); \
        GLOAD_LDS16(gB1 + (koff), &Bsm[b][(2 * w + 1) * 512]); \
    } while (0)

    const int fr = lane & 15, fq = lane >> 4;
    f32x4 acc[4][4] = {};

    const int nt = K >> 5;
    STAGE4(0, 0);
    __syncthreads();
    int cur = 0;
    for (int tt = 0; tt < nt; ++tt) {
        if (tt + 1 < nt) STAGE4(cur ^ 1, (tt + 1) * 32);
        short8 av[4], bv[4];
#pragma unroll
        for (int m = 0; m < 4; ++m)
            av[m] = *(const short8*)&Asm[cur][(wr * 64 + m * 16 + fr) * 32 + fq * 8];
#pragma unroll
        for (int n = 0; n < 4; ++n)
            bv[n] = *(const short8*)&Bsm[cur][(wc * 64 + n * 16 + fr) * 32 + fq * 8];
#pragma unroll
        for (int m = 0; m < 4; ++m)
#pragma unroll
            for (int n = 0; n < 4; ++n)
                acc[m][n] = __builtin_amdgcn_mfma_f32_16x16x32_bf16(av[m], bv[n], acc[m][n], 0, 0, 0);
        __syncthreads();
        cur ^= 1;
    }
#undef STAGE4

#pragma unroll
    for (int m = 0; m < 4; ++m) {
        int row0 = bm + wr * 64 + m * 16 + fq * 4;
#pragma unroll
        for (int n = 0; n < 4; ++n) {
            int col = bn + wc * 64 + n * 16 + fr;
#pragma unroll
            for (int rr = 0; rr < 4; ++rr) {
                if (CBF16)
                    Ch[(size_t)(row0 + rr) * N + col] = f2bf(acc[m][n][rr]);
                else
                    Cf[(size_t)(row0 + rr) * N + col] = acc[m][n][rr];
            }
        }
    }
}

// ---------------- launch ----------------

extern "C" void kernel_launch(void* const* d_in, const int* in_sizes, int n_in,
                              void* d_out, int out_size, void* d_ws, size_t ws_size,
                              hipStream_t stream) {
    const float* x1 = (const float*)d_in[0];
    const float* x2 = (const float*)d_in[1];
    const float* mask = (const float*)d_in[2];
    float* out = (float*)d_out;

    char* base = (char*)d_ws;
    const size_t LsLs = (size_t)Ls * Ls;
    const size_t LsCK = (size_t)Ls * CK;
    const long long sPQ = (long long)Ls * KG;

    const bool batched = ws_size >= 132175872ull;

    float* MM2 = (float*)(base);
    float* RN2 = (float*)(base + 20480);
    unsigned short *P, *Q, *ATb2, *RWT2;
    float *G, *S;
    unsigned short* T2 = (unsigned short*)base;   // bf16 overlay: 2 x 9.44MB = 18.9MB (dead region by then)
    if (batched) {
        P    = (unsigned short*)(base + 40960);
        Q    = (unsigned short*)(base + 3584000);
        G    = (float*)(base + 7127040);        // 2KB guards around
        S    = (float*)(base + 49598464);       // 2KB guards around
        ATb2 = (unsigned short*)(base + 92067840);
        RWT2 = (unsigned short*)(base + 113301504);   // end 132,175,872
    } else {
        P    = (unsigned short*)(base + 40960);
        Q    = (unsigned short*)(base + 1812480);
        G    = (float*)(base + 3586048);
        S    = (float*)(base + 24823808);
        ATb2 = (unsigned short*)(base + 46059520);
        RWT2 = (unsigned short*)(base + 67293184);    // end 86,167,552
    }

    mm_k<<<dim3(Ls / 256, 2), 256, 0, stream>>>(mask, MM2);
    gather_rwT_k<<<dim3(Ls / 256, CK, 2), 256, 0, stream>>>(x1, RWT2);

    const int tapsGrid = (Ls * 576) / 256;   // 5184

    if (batched) {
        transposePQ_k<<<dim3(2, Ls / 64, 2), 256, 0, stream>>>(x2, P, Q, sPQ, 0);
        mfma_gemm_k<0, 0><<<dim3(Ls / 128, Ls / 128, 2), 256, 0, stream>>>(
            P, Q, G, Ls, Ls, KG, sPQ, sPQ, (long long)LsLs);
        taps9rn_k<<<dim3(tapsGrid, 1, 2), 256, 0, stream>>>(G, S, RN2, (long long)LsLs, (long long)LsLs, 0);
        fuse12T_k<<<dim3(Ls / 64, Ls / 64, 2), 256, 0, stream>>>(S, RN2, G, (long long)LsLs, (long long)LsLs, 0);
        softmax_row_k<<<dim3(Ls / 4, 1, 2), 256, 0, stream>>>(G, MM2, ATb2, (long long)LsLs, 0);
    } else {
        for (int z0 = 0; z0 < 2; ++z0) {
            transposePQ_k<<<dim3(2, Ls / 64, 1), 256, 0, stream>>>(x2, P, Q, 0, z0);
            mfma_gemm_k<0, 0><<<dim3(Ls / 128, Ls / 128, 1), 256, 0, stream>>>(
                P, Q, G, Ls, Ls, KG, 0, 0, 0);
            taps9rn_k<<<dim3(tapsGrid, 1, 1), 256, 0, stream>>>(G, S, RN2, 0, 0, z0);
            fuse12T_k<<<dim3(Ls / 64, Ls / 64, 1), 256, 0, stream>>>(S, RN2, G, 0, 0, z0);
            softmax_row_k<<<dim3(Ls / 4, 1, 1), 256, 0, stream>>>(G, MM2, ATb2, 0, z0);
        }
    }

    // batched deconv GEMM (bf16 C) with 4x3 supertile swizzle: T = A^T @ RW for both samples
    mfma_gemm_k<1, 1><<<dim3(CK / 128, Ls / 128, 2), 256, 0, stream>>>(
        ATb2, RWT2, T2, Ls, CK, Ls,
        (long long)LsLs, (long long)LsCK, (long long)LsCK);

    scatter3_k<<<dim3(Cc, 2, 2), 256, 0, stream>>>(T2, out);

    (void)in_sizes; (void)n_in; (void)out_size; (void)ws_size;
}

// Round 7
// 222.126 us; speedup vs baseline: 4.6240x; 1.0074x over previous
//
#include <hip/hip_runtime.h>
#include <hip/hip_bf16.h>

// Problem constants (ContextualAttention):
//  B=2, C=128, H=W=96, rate=2 -> h=w=48, L=2304, kernel=4, KSIZE=3, SCALE=10
#define Cc   128
#define Hh   96
#define hs   48
#define Ls   2304      // 48*48
#define CK   2048      // C*16
#define KG   384       // Gram split-K: [h|lo|h] / [h|h|lo]

typedef __attribute__((ext_vector_type(8))) short short8;
typedef __attribute__((ext_vector_type(4))) float f32x4;

__device__ __forceinline__ unsigned short f2bf(float x) {
    unsigned int u = __float_as_uint(x);
    unsigned int r = (u + 0x7fff + ((u >> 16) & 1)) >> 16;   // RNE
    return (unsigned short)r;
}
__device__ __forceinline__ float bf2f(unsigned short h) {
    return __uint_as_float((unsigned)h << 16);
}

// unaligned-tolerant 16B vector load (addr is 4B-aligned)
__device__ __forceinline__ f32x4 ld4u(const float* p) {
    f32x4 v; __builtin_memcpy(&v, p, 16); return v;
}

#define GLOAD_LDS16(g, l) \
    __builtin_amdgcn_global_load_lds((__attribute__((address_space(1))) const void*)(g), \
                                     (__attribute__((address_space(3))) void*)(l), 16, 0, 0)

// ---------------- small kernels ----------------

// fused subsample + transpose + bf16 hi/lo split: x2 -> P,Q [l][384]
__global__ __launch_bounds__(256) void transposePQ_k(const float* __restrict__ x2,
                                                     unsigned short* __restrict__ P,
                                                     unsigned short* __restrict__ Q,
                                                     long long sPQ, int z0) {
    const int z = z0 + blockIdx.z;
    const float* x2b = x2 + (size_t)z * Cc * Hh * Hh;
    unsigned short* Pb = P + (size_t)blockIdx.z * sPQ;
    unsigned short* Qb = Q + (size_t)blockIdx.z * sPQ;
    __shared__ float tile[64][65];
    const int c0 = blockIdx.x * 64;      // 0 or 64
    const int l0 = blockIdx.y * 64;      // 36 tiles
    const int t = threadIdx.x;
    const int lt = t & 63, cg = t >> 6;  // cg 0..3
    const int l = l0 + lt;
    const int iy = l / hs, jx = l % hs;
    const int srcoff = iy * (2 * Hh) + 2 * jx;
#pragma unroll
    for (int cc = 0; cc < 16; ++cc) {
        int c = cg * 16 + cc;
        tile[lt][c] = x2b[(size_t)(c0 + c) * (Hh * Hh) + srcoff];
    }
    __syncthreads();
    const int lr = t >> 2, seg = t & 3;
    const int lw = l0 + lr;
    short8 hv0, hv1, lv0, lv1;
#pragma unroll
    for (int k = 0; k < 8; ++k) {
        float x = tile[lr][seg * 16 + k];
        unsigned short h = f2bf(x);
        float hf = __uint_as_float((unsigned)h << 16);
        unsigned short lo = f2bf(x - hf);
        hv0[k] = (short)h; lv0[k] = (short)lo;
    }
#pragma unroll
    for (int k = 0; k < 8; ++k) {
        float x = tile[lr][seg * 16 + 8 + k];
        unsigned short h = f2bf(x);
        float hf = __uint_as_float((unsigned)h << 16);
        unsigned short lo = f2bf(x - hf);
        hv1[k] = (short)h; lv1[k] = (short)lo;
    }
    size_t rowp = (size_t)lw * KG;
    int coff = c0 + seg * 16;
    *(short8*)&Pb[rowp + coff] = hv0;        *(short8*)&Pb[rowp + coff + 8] = hv1;
    *(short8*)&Pb[rowp + 128 + coff] = lv0;  *(short8*)&Pb[rowp + 128 + coff + 8] = lv1;
    *(short8*)&Pb[rowp + 256 + coff] = hv0;  *(short8*)&Pb[rowp + 256 + coff + 8] = hv1;
    *(short8*)&Qb[rowp + coff] = hv0;        *(short8*)&Qb[rowp + coff + 8] = hv1;
    *(short8*)&Qb[rowp + 128 + coff] = hv0;  *(short8*)&Qb[rowp + 128 + coff + 8] = hv1;
    *(short8*)&Qb[rowp + 256 + coff] = lv0;  *(short8*)&Qb[rowp + 256 + coff + 8] = lv1;
}

__global__ __launch_bounds__(256) void mm_k(const float* __restrict__ mask, float* __restrict__ MM) {
    int z = blockIdx.y;
    const float* mb = mask + (size_t)z * hs * hs;
    float* MMb = MM + (size_t)z * Ls;
    int l = blockIdx.x * 256 + threadIdx.x;
    if (l >= Ls) return;
    int ly = l / hs, lx = l % hs;
    float s = 0.f;
    for (int dy = -1; dy <= 1; ++dy)
        for (int dx = -1; dx <= 1; ++dx) {
            int yy = ly + dy, xx = lx + dx;
            if ((unsigned)yy < (unsigned)hs && (unsigned)xx < (unsigned)hs) s += mb[yy * hs + xx];
        }
    float m = s * (1.0f / 9.0f);
    MMb[l] = (m == 0.0f) ? 1.0f : 0.0f;
}

// fused taps + rnorm, vectorized: each thread computes 4 consecutive j for one i.
// G must have >=2KB guard bands on both sides.
__global__ __launch_bounds__(256) void taps9rn_k(const float* __restrict__ G, float* __restrict__ S,
                                                 float* __restrict__ RN, long long zsG, long long zsS, int z0) {
    const float* Gb = G + (size_t)blockIdx.z * zsG;
    float* Sb = S + (size_t)blockIdx.z * zsS;
    float* RNb = RN + (size_t)(z0 + blockIdx.z) * Ls;
    int g = blockIdx.x * 256 + threadIdx.x;      // < 2304*576
    int i = g / 576;
    int jb = (g - i * 576) * 4;
    int iy = i / hs, ix = i % hs;
    int jy = jb / hs, jx0 = jb % hs;
    f32x4 acc = {};
#pragma unroll
    for (int dy = -1; dy <= 1; ++dy) {
        int vy = ((unsigned)(iy + dy) < (unsigned)hs) && ((unsigned)(jy + dy) < (unsigned)hs);
#pragma unroll
        for (int dx = -1; dx <= 1; ++dx) {
            int vi = vy && ((unsigned)(ix + dx) < (unsigned)hs);
            int o = hs * dy + dx;
            int row = vi ? (i + o) : i;
            f32x4 v = ld4u(&Gb[(size_t)row * Ls + jb + o]);
            f32x4 m;
#pragma unroll
            for (int ln = 0; ln < 4; ++ln)
                m[ln] = (vi && ((unsigned)(jx0 + ln + dx) < (unsigned)hs)) ? 1.f : 0.f;
            acc += v * m;
        }
    }
    __builtin_memcpy(&Sb[(size_t)i * Ls + jb], &acc, 16);
    int dd = i - jb;
    if ((unsigned)dd < 4u) RNb[i] = 1.0f / fmaxf(sqrtf(acc[dd]), 1e-4f);
}

// fused fuse2(fuse1) with transposed output, vectorized 4j x 4i per thread.
// S must have >=2KB guard bands on both sides.
__global__ __launch_bounds__(256) void fuse12T_k(const float* __restrict__ S, const float* __restrict__ RN,
                                                 float* __restrict__ ZT, long long zsS, long long zsZT, int z0) {
    const float* Sb = S + (size_t)blockIdx.z * zsS;
    float* ZTb = ZT + (size_t)blockIdx.z * zsZT;
    const float* RNb = RN + (size_t)(z0 + blockIdx.z) * Ls;
    __shared__ float tile[64][65];
    const int i0 = blockIdx.y * 64, j0 = blockIdx.x * 64;
    const int t = threadIdx.x;
    const int jg = t & 15, tit = t >> 4;
    const int jb = j0 + jg * 4;
    const int jy0 = jb / hs, jx0 = jb % hs;

    int ccb[9]; f32x4 m4[9];
#pragma unroll
    for (int d2 = -1; d2 <= 1; ++d2) {
        int cl[4], vb[4];
#pragma unroll
        for (int ln = 0; ln < 4; ++ln) {
            int j2 = (jx0 + ln) * hs + jy0 + d2;
            int vv = ((unsigned)j2 < (unsigned)Ls) ? 1 : 0;
            int c = vv ? ((j2 % hs) * hs + j2 / hs) : 0;
            cl[ln] = c; vb[ln] = vv;
        }
        int base = 0;
#pragma unroll
        for (int ln = 0; ln < 4; ++ln) if (vb[ln]) base = cl[ln] - ln;
#pragma unroll
        for (int d1 = -1; d1 <= 1; ++d1) {
            int idx = (d2 + 1) * 3 + (d1 + 1);
            ccb[idx] = base + d1;
            f32x4 mm;
#pragma unroll
            for (int ln = 0; ln < 4; ++ln) {
                int cc = cl[ln] + d1;
                mm[ln] = (vb[ln] && ((unsigned)cc < (unsigned)Ls)) ? 1.f : 0.f;
            }
            m4[idx] = mm;
        }
    }

    f32x4 acc[4] = {};
#pragma unroll
    for (int kk = 0; kk < 4; ++kk) {
        const int i = i0 + tit * 4 + kk;
        const int iy = i / hs, ix = i % hs;
        const int tif = ix * hs + iy;
#pragma unroll
        for (int d2 = -1; d2 <= 1; ++d2) {
            int i2 = tif + d2;
            int vi = ((unsigned)i2 < (unsigned)Ls) ? 1 : 0;
            int r = vi ? ((i2 % hs) * hs + i2 / hs) : 1;
#pragma unroll
            for (int d1 = -1; d1 <= 1; ++d1) {
                int rr = r + d1;
                int vr = vi && ((unsigned)rr < (unsigned)Ls);
                int rrc = vr ? rr : 0;
                float w = RNb[rrc];
                w = vr ? w : 0.f;
                int idx = (d2 + 1) * 3 + (d1 + 1);
                f32x4 v = ld4u(&Sb[(size_t)rrc * Ls + ccb[idx]]);
                acc[kk] += v * m4[idx] * w;
            }
        }
    }
#pragma unroll
    for (int kk = 0; kk < 4; ++kk) {
        int ti = tit * 4 + kk;
        tile[ti][jg * 4 + 0] = acc[kk][0];
        tile[ti][jg * 4 + 1] = acc[kk][1];
        tile[ti][jg * 4 + 2] = acc[kk][2];
        tile[ti][jg * 4 + 3] = acc[kk][3];
    }
    __syncthreads();
    const int r2 = t >> 2, cs = (t & 3) * 16;
    float vbuf[16];
#pragma unroll
    for (int k = 0; k < 16; ++k) vbuf[k] = tile[cs + k][r2];
    float* dst = &ZTb[(size_t)(j0 + r2) * Ls + i0 + cs];
#pragma unroll
    for (int k = 0; k < 4; ++k)
        *(float4*)&dst[k * 4] = *(float4*)&vbuf[k * 4];
}

// row softmax over ZT[p][l] (coalesced), writes bf16 AT[p][l]
__global__ __launch_bounds__(256) void softmax_row_k(const float* __restrict__ ZT, const float* __restrict__ MM,
                                                     unsigned short* __restrict__ AT, long long zsZT, int z0) {
    const int z = z0 + blockIdx.z;
    const float* ZTb = ZT + (size_t)blockIdx.z * zsZT;
    const float* MMb = MM + (size_t)z * Ls;
    unsigned short* ATb = AT + (size_t)z * Ls * Ls;
    const int w = threadIdx.x >> 6, lane = threadIdx.x & 63;
    const int p = blockIdx.x * 4 + w;
    const float* row = ZTb + (size_t)p * Ls;
    float v[36];
    float mx = -3.4e38f;
#pragma unroll
    for (int k = 0; k < 9; ++k) {
        const float4 zv = *(const float4*)&row[k * 256 + lane * 4];
        const float4 m = *(const float4*)&MMb[k * 256 + lane * 4];
        v[4 * k + 0] = zv.x * m.x * 10.f;
        v[4 * k + 1] = zv.y * m.y * 10.f;
        v[4 * k + 2] = zv.z * m.z * 10.f;
        v[4 * k + 3] = zv.w * m.w * 10.f;
        mx = fmaxf(mx, fmaxf(fmaxf(v[4 * k], v[4 * k + 1]), fmaxf(v[4 * k + 2], v[4 * k + 3])));
    }
#pragma unroll
    for (int off = 32; off; off >>= 1) mx = fmaxf(mx, __shfl_xor(mx, off));
    float sum = 0.f;
#pragma unroll
    for (int kk = 0; kk < 36; ++kk) { v[kk] = expf(v[kk] - mx); sum += v[kk]; }
#pragma unroll
    for (int off = 32; off; off >>= 1) sum += __shfl_xor(sum, off);
    const float rs = 1.0f / sum;
#pragma unroll
    for (int k = 0; k < 9; ++k) {
        const float4 m = *(const float4*)&MMb[k * 256 + lane * 4];
        ushort4 o;
        o.x = f2bf(fmaxf(v[4 * k + 0] * rs * m.x, 1e-8f));
        o.y = f2bf(fmaxf(v[4 * k + 1] * rs * m.y, 1e-8f));
        o.z = f2bf(fmaxf(v[4 * k + 2] * rs * m.z, 1e-8f));
        o.w = f2bf(fmaxf(v[4 * k + 3] * rs * m.w, 1e-8f));
        *(ushort4*)&ATb[(size_t)p * Ls + k * 256 + lane * 4] = o;
    }
}

// raw_w^T gather (bf16, N-major K-contiguous), z-batched
__global__ __launch_bounds__(256) void gather_rwT_k(const float* __restrict__ x1, unsigned short* __restrict__ RWT) {
    const int z = blockIdx.z;
    const float* x1b = x1 + (size_t)z * Cc * Hh * Hh;
    unsigned short* R = RWT + (size_t)z * CK * Ls;
    int l = blockIdx.x * 256 + threadIdx.x;   // < 2304
    int ck = blockIdx.y;                      // < 2048
    int c = ck >> 4, a = (ck >> 2) & 3, b2 = ck & 3;
    int ly = l / hs, lx = l % hs;
    int u = 2 * ly + a - 1, vv = 2 * lx + b2 - 1;
    float val = ((unsigned)u < (unsigned)Hh && (unsigned)vv < (unsigned)Hh) ? x1b[c * (Hh * Hh) + u * Hh + vv] : 0.0f;
    R[(size_t)ck * Ls + l] = f2bf(val);
}

// LDS-gather scatter: block = (channel, yhalf, z); T is bf16.
__global__ __launch_bounds__(256) void scatter3_k(const unsigned short* __restrict__ T, float* __restrict__ out) {
    const int z = blockIdx.z;
    const int c = blockIdx.x;
    const int yh = blockIdx.y;                 // 0 or 1
    const unsigned short* Tb = T + (size_t)z * Ls * CK + (size_t)c * 16;
    float* outb = out + (size_t)z * Cc * Hh * Hh + (size_t)c * Hh * Hh;
    const int i0 = (yh == 0) ? 0 : 23;          // i range [i0, i0+25)
    __shared__ unsigned short Tl[1200 * 16];    // 25*48 rows x 16 bf16 = 38.4 KB
    const int t = threadIdx.x;
#pragma unroll
    for (int rep = 0; rep < 5; ++rep) {
        int p = rep * 256 + t;
        if (p < 1200)
            __builtin_memcpy(&Tl[p * 16], &Tb[(size_t)(i0 * hs + p) * CK], 32);
    }
    __syncthreads();
#pragma unroll
    for (int rep = 0; rep < 5; ++rep) {
        int idx4 = rep * 256 + t;              // < 1152 (48 rows x 24 float4)
        if (idx4 >= 1152) break;
        int Y = yh * 48 + idx4 / 24;
        int X0 = (idx4 % 24) * 4;
        float o4[4];
#pragma unroll
        for (int xi = 0; xi < 4; ++xi) {
            int X = X0 + xi;
            int a0 = (Y + 1) & 1, b0 = (X + 1) & 1;
            float s = 0.f;
#pragma unroll
            for (int ai = 0; ai < 2; ++ai) {
                int a = a0 + 2 * ai;
                int i = (Y + 1 - a) >> 1;
                if ((unsigned)i >= (unsigned)hs) continue;
#pragma unroll
                for (int bi = 0; bi < 2; ++bi) {
                    int b2 = b0 + 2 * bi;
                    int jj = (X + 1 - b2) >> 1;
                    if ((unsigned)jj >= (unsigned)hs) continue;
                    s += bf2f(Tl[((i - i0) * hs + jj) * 16 + a * 4 + b2]);
                }
            }
            o4[xi] = 0.25f * s;
        }
        *(float4*)&outb[Y * Hh + X0] = *(float4*)&o4[0];
    }
}

// ---------------- bf16 MFMA GEMM, 2-phase double-buffered, LDS slot-swizzled ----------------
// C[M,N] = A[M,K] * Bt[N,K]^T, z-batched. SUPER: 4x3 supertile remap (grid must be 16x18).
// CBF16: C written as bf16, else f32.
// LDS layout: within each row's 64B, 16B slot s stores logical kslot (s ^ ((row>>1)&3)).
// Staged via pre-swizzled GLOBAL source (LDS dest stays linear, per global_load_lds rules);
// reads XOR the same pattern -> ds_read_b128 goes 8-way -> 2-way bank conflict (free).
template <int SUPER, int CBF16>
__global__ __launch_bounds__(256) void mfma_gemm_k(const unsigned short* __restrict__ A,
                                                   const unsigned short* __restrict__ Bt,
                                                   void* __restrict__ Cv, int M, int N, int K,
                                                   long long sA, long long sB, long long sC) {
    A  += (size_t)blockIdx.z * sA;
    Bt += (size_t)blockIdx.z * sB;
    float* Cf = (float*)Cv + (CBF16 ? 0 : (size_t)blockIdx.z * sC);
    unsigned short* Ch = (unsigned short*)Cv + (CBF16 ? (size_t)blockIdx.z * sC : 0);

    // bijective XCD-aware remap over (x,y)
    const int nb = gridDim.x * gridDim.y;
    const int flat = blockIdx.y * gridDim.x + blockIdx.x;
    const int q = nb >> 3, r = nb & 7;
    const int xcd = flat & 7, sidx = flat >> 3;
    const int wg = (xcd < r ? xcd * (q + 1) : r * (q + 1) + (xcd - r) * q) + sidx;
    int bm, bn;
    if (SUPER) {
        int st = wg / 12, tt = wg % 12;
        int stn = st & 3, stm = st >> 2;     // 4 x 6 supertile grid
        int tn = tt & 3, tm = tt >> 2;       // 4(n) x 3(m) within
        bn = (stn * 4 + tn) * 128;
        bm = (stm * 3 + tm) * 128;
    } else {
        bm = (wg / gridDim.x) * 128;
        bn = (wg % gridDim.x) * 128;
    }

    __shared__ __align__(16) unsigned short Asm[2][128 * 32];
    __shared__ __align__(16) unsigned short Bsm[2][128 * 32];
    const int t = threadIdx.x;
    const int lane = t & 63, w = t >> 6;
    const int wr = w >> 1, wc = w & 1;

    // staging: lane ln writes LDS bytes [q*1024 + ln*16) linearly -> row rA, phys slot (lane&3).
    // logical kslot for that phys slot = (lane&3) ^ ((rA>>1)&3) = (lane&3) ^ ((lane>>3)&3).
    const int rA = 32 * w + (lane >> 2);
    const int kA = (((lane & 3) ^ ((lane >> 3) & 3))) * 8;
    const unsigned short* gA0 = A + (size_t)(bm + rA) * K + kA;
    const unsigned short* gA1 = gA0 + (size_t)16 * K;   // row rA+16: same swizzle ((rA+16)>>1 & 3 == (rA>>1)&3)
    const unsigned short* gB0 = Bt + (size_t)(bn + rA) * K + kA;
    const unsigned short* gB1 = gB0 + (size_t)16 * K;

#define STAGE4(b, koff) do { \
        GLOAD_LDS16(gA0 + (koff), &Asm[b][(2 * w) * 512]); \
        GLOAD_LDS16(gA1 + (koff), &Asm[b][(2 * w + 1) * 512]); \
        GLOAD_LDS16(gB0 + (koff), &Bsm[b][(2 * w) * 512]); \
        GLOAD_LDS16(gB1 + (koff), &Bsm[b][(2 * w + 1) * 512]); \
    } while (0)

    const int fr = lane & 15, fq = lane >> 4;
    const int sxa = (fr >> 1) & 3;          // read-side swizzle: rows wr*64+m*16+fr all share (row>>1)&3 = (fr>>1)&3
    const int sqa = (fq ^ sxa) * 8;
    f32x4 acc[4][4] = {};

    const int nt = K >> 5;
    STAGE4(0, 0);
    __syncthreads();
    int cur = 0;
    for (int tt = 0; tt < nt; ++tt) {
        if (tt + 1 < nt) STAGE4(cur ^ 1, (tt + 1) * 32);
        short8 av[4], bv[4];
#pragma unroll
        for (int m = 0; m < 4; ++m)
            av[m] = *(const short8*)&Asm[cur][(wr * 64 + m * 16 + fr) * 32 + sqa];
#pragma unroll
        for (int n = 0; n < 4; ++n)
            bv[n] = *(const short8*)&Bsm[cur][(wc * 64 + n * 16 + fr) * 32 + sqa];
#pragma unroll
        for (int m = 0; m < 4; ++m)
#pragma unroll
            for (int n = 0; n < 4; ++n)
                acc[m][n] = __builtin_amdgcn_mfma_f32_16x16x32_bf16(av[m], bv[n], acc[m][n], 0, 0, 0);
        __syncthreads();
        cur ^= 1;
    }
#undef STAGE4

#pragma unroll
    for (int m = 0; m < 4; ++m) {
        int row0 = bm + wr * 64 + m * 16 + fq * 4;
#pragma unroll
        for (int n = 0; n < 4; ++n) {
            int col = bn + wc * 64 + n * 16 + fr;
#pragma unroll
            for (int rr = 0; rr < 4; ++rr) {
                if (CBF16)
                    Ch[(size_t)(row0 + rr) * N + col] = f2bf(acc[m][n][rr]);
                else
                    Cf[(size_t)(row0 + rr) * N + col] = acc[m][n][rr];
            }
        }
    }
}

// ---------------- launch ----------------

extern "C" void kernel_launch(void* const* d_in, const int* in_sizes, int n_in,
                              void* d_out, int out_size, void* d_ws, size_t ws_size,
                              hipStream_t stream) {
    const float* x1 = (const float*)d_in[0];
    const float* x2 = (const float*)d_in[1];
    const float* mask = (const float*)d_in[2];
    float* out = (float*)d_out;

    char* base = (char*)d_ws;
    const size_t LsLs = (size_t)Ls * Ls;
    const size_t LsCK = (size_t)Ls * CK;
    const long long sPQ = (long long)Ls * KG;

    const bool batched = ws_size >= 132175872ull;

    float* MM2 = (float*)(base);
    float* RN2 = (float*)(base + 20480);
    unsigned short *P, *Q, *ATb2, *RWT2;
    float *G, *S;
    unsigned short* T2 = (unsigned short*)base;   // bf16 overlay: 2 x 9.44MB = 18.9MB (dead region by then)
    if (batched) {
        P    = (unsigned short*)(base + 40960);
        Q    = (unsigned short*)(base + 3584000);
        G    = (float*)(base + 7127040);        // 2KB guards around
        S    = (float*)(base + 49598464);       // 2KB guards around
        ATb2 = (unsigned short*)(base + 92067840);
        RWT2 = (unsigned short*)(base + 113301504);   // end 132,175,872
    } else {
        P    = (unsigned short*)(base + 40960);
        Q    = (unsigned short*)(base + 1812480);
        G    = (float*)(base + 3586048);
        S    = (float*)(base + 24823808);
        ATb2 = (unsigned short*)(base + 46059520);
        RWT2 = (unsigned short*)(base + 67293184);    // end 86,167,552
    }

    mm_k<<<dim3(Ls / 256, 2), 256, 0, stream>>>(mask, MM2);
    gather_rwT_k<<<dim3(Ls / 256, CK, 2), 256, 0, stream>>>(x1, RWT2);

    const int tapsGrid = (Ls * 576) / 256;   // 5184

    if (batched) {
        transposePQ_k<<<dim3(2, Ls / 64, 2), 256, 0, stream>>>(x2, P, Q, sPQ, 0);
        mfma_gemm_k<0, 0><<<dim3(Ls / 128, Ls / 128, 2), 256, 0, stream>>>(
            P, Q, G, Ls, Ls, KG, sPQ, sPQ, (long long)LsLs);
        taps9rn_k<<<dim3(tapsGrid, 1, 2), 256, 0, stream>>>(G, S, RN2, (long long)LsLs, (long long)LsLs, 0);
        fuse12T_k<<<dim3(Ls / 64, Ls / 64, 2), 256, 0, stream>>>(S, RN2, G, (long long)LsLs, (long long)LsLs, 0);
        softmax_row_k<<<dim3(Ls / 4, 1, 2), 256, 0, stream>>>(G, MM2, ATb2, (long long)LsLs, 0);
    } else {
        for (int z0 = 0; z0 < 2; ++z0) {
            transposePQ_k<<<dim3(2, Ls / 64, 1), 256, 0, stream>>>(x2, P, Q, 0, z0);
            mfma_gemm_k<0, 0><<<dim3(Ls / 128, Ls / 128, 1), 256, 0, stream>>>(
                P, Q, G, Ls, Ls, KG, 0, 0, 0);
            taps9rn_k<<<dim3(tapsGrid, 1, 1), 256, 0, stream>>>(G, S, RN2, 0, 0, z0);
            fuse12T_k<<<dim3(Ls / 64, Ls / 64, 1), 256, 0, stream>>>(S, RN2, G, 0, 0, z0);
            softmax_row_k<<<dim3(Ls / 4, 1, 1), 256, 0, stream>>>(G, MM2, ATb2, 0, z0);
        }
    }

    // batched deconv GEMM (bf16 C) with 4x3 supertile swizzle: T = A^T @ RW for both samples
    mfma_gemm_k<1, 1><<<dim3(CK / 128, Ls / 128, 2), 256, 0, stream>>>(
        ATb2, RWT2, T2, Ls, CK, Ls,
        (long long)LsLs, (long long)LsCK, (long long)LsCK);

    scatter3_k<<<dim3(Cc, 2, 2), 256, 0, stream>>>(T2, out);

    (void)in_sizes; (void)n_in; (void)out_size; (void)ws_size;
}